// Round 1
// baseline (764.805 us; speedup 1.0000x reference)
//
#include <hip/hip_runtime.h>
#include <hip/hip_bf16.h>
#include <math.h>

#define Bb 2
#define NQn 256
#define NSn 1024
#define Dn 256
#define Hn 8
#define DHn 32
#define FFNn 1024
#define RPEn 512
#define SCALEf 0.17677669529663687f
#define EPSf 1e-5f

// ---------------------------------------------------------------------------
// Generic tiled f32 GEMM: C[M,N] = act( (A(+A2)) @ W^T + bias ) * scale
// W is row-major [N,K] (torch-style). 64x64 tile, 256 threads, 4x4 per thread.
// ---------------------------------------------------------------------------
__global__ __launch_bounds__(256) void gemm_kernel(
    float* __restrict__ C, const float* __restrict__ A, const float* __restrict__ A2,
    const float* __restrict__ W, const float* __restrict__ bias,
    int M, int N, int K, float scale, int do_relu)
{
  __shared__ float As[64][17];
  __shared__ float Ws[64][17];
  const int bm = blockIdx.y * 64;
  const int bn = blockIdx.x * 64;
  const int tid = threadIdx.x;
  const int tx = tid & 15, ty = tid >> 4;
  float acc[4][4];
#pragma unroll
  for (int i = 0; i < 4; ++i)
#pragma unroll
    for (int j = 0; j < 4; ++j) acc[i][j] = 0.f;

  for (int k0 = 0; k0 < K; k0 += 16) {
#pragma unroll
    for (int u = 0; u < 4; ++u) {
      int t = tid + u * 256;
      int m = t >> 4, k = t & 15;
      size_t ga = (size_t)(bm + m) * K + k0 + k;
      float v = A[ga];
      if (A2) v += A2[ga];
      As[m][k] = v;
      Ws[m][k] = W[(size_t)(bn + m) * K + k0 + k];
    }
    __syncthreads();
#pragma unroll
    for (int k = 0; k < 16; ++k) {
      float a[4], w[4];
#pragma unroll
      for (int i = 0; i < 4; ++i) a[i] = As[ty * 4 + i][k];
#pragma unroll
      for (int j = 0; j < 4; ++j) w[j] = Ws[tx * 4 + j][k];
#pragma unroll
      for (int i = 0; i < 4; ++i)
#pragma unroll
        for (int j = 0; j < 4; ++j) acc[i][j] += a[i] * w[j];
    }
    __syncthreads();
  }

#pragma unroll
  for (int i = 0; i < 4; ++i) {
    int m = bm + ty * 4 + i;
#pragma unroll
    for (int j = 0; j < 4; ++j) {
      int n = bn + tx * 4 + j;
      float v = acc[i][j];
      if (bias) v += bias[n];
      v *= scale;
      if (do_relu) v = fmaxf(v, 0.f);
      C[(size_t)m * N + n] = v;
    }
  }
}

// ---------------------------------------------------------------------------
// Batched attention logits: S[b,h,q,k] = sum_dh Q[b,q,h*32+dh] * K[b,k,h*32+dh]
// grid: (NK/64, NQ/64, B*H)
// ---------------------------------------------------------------------------
__global__ __launch_bounds__(256) void logits_kernel(
    float* __restrict__ S, const float* __restrict__ Q, const float* __restrict__ Km,
    int NQr, int NKr)
{
  __shared__ float Qs[64][33];
  __shared__ float Ks[64][33];
  const int bh = blockIdx.z;
  const int b = bh >> 3, h = bh & 7;
  const int q0 = blockIdx.y * 64, k0 = blockIdx.x * 64;
  const int tid = threadIdx.x;
#pragma unroll
  for (int u = 0; u < 8; ++u) {
    int t = tid + u * 256;
    int r = t >> 5, c = t & 31;
    Qs[r][c] = Q[((size_t)(b * NQr + q0 + r)) * Dn + h * DHn + c];
    Ks[r][c] = Km[((size_t)(b * NKr + k0 + r)) * Dn + h * DHn + c];
  }
  __syncthreads();
  const int tx = tid & 15, ty = tid >> 4;
  float acc[4][4] = {};
#pragma unroll
  for (int d = 0; d < 32; ++d) {
    float a[4], w[4];
#pragma unroll
    for (int i = 0; i < 4; ++i) a[i] = Qs[ty * 4 + i][d];
#pragma unroll
    for (int j = 0; j < 4; ++j) w[j] = Ks[tx * 4 + j][d];
#pragma unroll
    for (int i = 0; i < 4; ++i)
#pragma unroll
      for (int j = 0; j < 4; ++j) acc[i][j] += a[i] * w[j];
  }
#pragma unroll
  for (int i = 0; i < 4; ++i) {
    int q = q0 + ty * 4 + i;
#pragma unroll
    for (int j = 0; j < 4; ++j) {
      int k = k0 + tx * 4 + j;
      S[((size_t)bh * NQr + q) * NKr + k] = acc[i][j];
    }
  }
}

// ---------------------------------------------------------------------------
// Softmax over rows of S (length NKr), optionally adding the piecewise-linear
// RPE bias (binary search in sorted breakpoints) and -100*pad_mask.
// grid: B*H*NQ blocks of 256.
// ---------------------------------------------------------------------------
__global__ __launch_bounds__(256) void softmax_kernel(
    float* __restrict__ S, int NKr,
    const float* __restrict__ rel, const float* __restrict__ pad,
    const float* __restrict__ tsg, const float* __restrict__ Stab,
    const float* __restrict__ Btab)
{
  const int row = blockIdx.x;
  const int q = row & (NQn - 1);
  const int bh = row >> 8;
  const int h = bh & 7, b = bh >> 3;
  float* Srow = S + (size_t)row * NKr;

  __shared__ float ts[RPEn];
  __shared__ float Sh[RPEn + 1];
  __shared__ float Bh[RPEn + 1];
  __shared__ float red[8];

  const bool use_bias = (rel != nullptr);
  if (use_bias) {
    for (int i = threadIdx.x; i < RPEn; i += 256) ts[i] = tsg[i];
    for (int i = threadIdx.x; i < RPEn + 1; i += 256) {
      Sh[i] = Stab[i * Hn + h];
      Bh[i] = Btab[i * Hn + h];
    }
    __syncthreads();
  }

  float vals[4];
  const int nper = NKr >> 8;  // 1 (self) or 4 (cross)
  float mymax = -3.0e38f;
  for (int it = 0; it < nper; ++it) {
    int k = threadIdx.x + (it << 8);
    float v = Srow[k];
    if (use_bias) {
      float m = rel[((size_t)b * NQn + q) * NKr + k];
      int lo = 0, hi = RPEn;
      while (lo < hi) {
        int mid = (lo + hi) >> 1;
        if (ts[mid] < m) lo = mid + 1; else hi = mid;
      }
      v += Sh[lo] * m + Bh[lo];
      v += pad[b * NKr + k] * -100.0f;
    }
    vals[it] = v;
    mymax = fmaxf(mymax, v);
  }

  float wm = mymax;
#pragma unroll
  for (int off = 32; off > 0; off >>= 1) wm = fmaxf(wm, __shfl_down(wm, off));
  const int lane = threadIdx.x & 63, wid = threadIdx.x >> 6;
  if (lane == 0) red[wid] = wm;
  __syncthreads();
  if (threadIdx.x == 0) red[4] = fmaxf(fmaxf(red[0], red[1]), fmaxf(red[2], red[3]));
  __syncthreads();
  const float rowmax = red[4];

  float wsum = 0.f;
  for (int it = 0; it < nper; ++it) {
    vals[it] = __expf(vals[it] - rowmax);
    wsum += vals[it];
  }
#pragma unroll
  for (int off = 32; off > 0; off >>= 1) wsum += __shfl_down(wsum, off);
  if (lane == 0) red[wid] = wsum;
  __syncthreads();
  if (threadIdx.x == 0) red[5] = red[0] + red[1] + red[2] + red[3];
  __syncthreads();
  const float inv = 1.f / red[5];
  for (int it = 0; it < nper; ++it) {
    int k = threadIdx.x + (it << 8);
    Srow[k] = vals[it] * inv;
  }
}

// ---------------------------------------------------------------------------
// PV: O[b,q,h*32+dh] = sum_k P[b,h,q,k] * V[b,k,h*32+dh]
// grid: (NQ/64, B*H)
// ---------------------------------------------------------------------------
__global__ __launch_bounds__(256) void pv_kernel(
    float* __restrict__ O, const float* __restrict__ P, const float* __restrict__ V,
    int NQr, int NKr)
{
  __shared__ float Ps[64][33];
  __shared__ float Vs[32][33];
  const int bh = blockIdx.y;
  const int b = bh >> 3, h = bh & 7;
  const int q0 = blockIdx.x * 64;
  const int tid = threadIdx.x;
  const int dh = tid & 31, tq = tid >> 5;
  float acc[8] = {};
  for (int k0 = 0; k0 < NKr; k0 += 32) {
#pragma unroll
    for (int u = 0; u < 8; ++u) {
      int t = tid + u * 256;
      int r = t >> 5, c = t & 31;
      Ps[r][c] = P[((size_t)bh * NQr + q0 + r) * NKr + k0 + c];
    }
#pragma unroll
    for (int u = 0; u < 4; ++u) {
      int t = tid + u * 256;
      int r = t >> 5, c = t & 31;
      Vs[r][c] = V[((size_t)(b * NKr + k0 + r)) * Dn + h * DHn + c];
    }
    __syncthreads();
#pragma unroll
    for (int kk = 0; kk < 32; ++kk) {
      float vv = Vs[kk][dh];
#pragma unroll
      for (int i = 0; i < 8; ++i) acc[i] += Ps[tq * 8 + i][kk] * vv;
    }
    __syncthreads();
  }
#pragma unroll
  for (int i = 0; i < 8; ++i)
    O[((size_t)(b * NQr + q0 + tq * 8 + i)) * Dn + h * DHn + dh] = acc[i];
}

// ---------------------------------------------------------------------------
// out = LayerNorm(x1 + x2) * g + b.  grid: B*NQ rows, block = 256 = D.
// ---------------------------------------------------------------------------
__global__ __launch_bounds__(256) void add_ln_kernel(
    float* __restrict__ out, const float* __restrict__ x1, const float* __restrict__ x2,
    const float* __restrict__ g, const float* __restrict__ bt)
{
  const int row = blockIdx.x;
  const int t = threadIdx.x;
  const float v = x1[(size_t)row * Dn + t] + x2[(size_t)row * Dn + t];
  float s = v, s2 = v * v;
#pragma unroll
  for (int off = 32; off > 0; off >>= 1) {
    s += __shfl_down(s, off);
    s2 += __shfl_down(s2, off);
  }
  __shared__ float rs[4], rs2[4], fin[2];
  const int lane = t & 63, wid = t >> 6;
  if (lane == 0) { rs[wid] = s; rs2[wid] = s2; }
  __syncthreads();
  if (t == 0) {
    float a = rs[0] + rs[1] + rs[2] + rs[3];
    float a2 = rs2[0] + rs2[1] + rs2[2] + rs2[3];
    float mean = a * (1.f / Dn);
    float var = a2 * (1.f / Dn) - mean * mean;
    fin[0] = mean;
    fin[1] = rsqrtf(var + EPSf);
  }
  __syncthreads();
  out[(size_t)row * Dn + t] = (v - fin[0]) * fin[1] * g[t] + bt[t];
}

// ---------------------------------------------------------------------------
// Build piecewise-linear tables for the RPE bias:
//   bias_h(m) = Stot[j][h]*m + Btot[j][h],  j = #{ t_sorted < m }
// One block, 512 threads. Bitonic sort of breakpoints + per-head prefix sums.
// ---------------------------------------------------------------------------
__global__ void build_cpb_tables(
    const float* __restrict__ w1p, const float* __restrict__ b1p,
    const float* __restrict__ w2p,
    float* __restrict__ tout, float* __restrict__ Stab, float* __restrict__ Btab)
{
  __shared__ float key[RPEn];
  __shared__ int pidx[RPEn];
  __shared__ float w1s[RPEn];
  __shared__ float b1s[RPEn];
  const int tid = threadIdx.x;
  {
    float w = w1p[tid], bb = b1p[tid];
    key[tid] = (w != 0.f) ? (-bb / w) : 3.0e38f;
    pidx[tid] = tid;
  }
  __syncthreads();
  for (int k = 2; k <= RPEn; k <<= 1) {
    for (int j = k >> 1; j > 0; j >>= 1) {
      int ixj = tid ^ j;
      if (ixj > tid) {
        float a = key[tid], c = key[ixj];
        bool asc = ((tid & k) == 0);
        bool sw = asc ? (a > c) : (a < c);
        if (sw) {
          key[tid] = c; key[ixj] = a;
          int tmp = pidx[tid]; pidx[tid] = pidx[ixj]; pidx[ixj] = tmp;
        }
      }
      __syncthreads();
    }
  }
  w1s[tid] = w1p[pidx[tid]];
  b1s[tid] = b1p[pidx[tid]];
  tout[tid] = key[tid];
  __syncthreads();
  if (tid < Hn) {
    const int h = tid;
    // forward: exclusive prefix over positive-slope terms (active when m > t)
    float sp = 0.f, bp = 0.f;
    for (int j = 0; j <= RPEn; ++j) {
      Stab[j * Hn + h] = sp;
      Btab[j * Hn + h] = bp;
      if (j < RPEn) {
        float w = w1s[j];
        if (w > 0.f) {
          float c = w2p[h * RPEn + pidx[j]];
          sp += w * c;
          bp += b1s[j] * c;
        }
      }
    }
    // constant contribution of zero-slope terms
    float cc = 0.f;
    for (int i = 0; i < RPEn; ++i)
      if (w1s[i] == 0.f) cc += fmaxf(b1s[i], 0.f) * w2p[h * RPEn + pidx[i]];
    // backward: suffix over negative-slope terms (active when m < t)
    float sn = 0.f, bn = 0.f;
    for (int j = RPEn; j >= 0; --j) {
      Stab[j * Hn + h] += sn;
      Btab[j * Hn + h] += bn + cc;
      if (j > 0) {
        float w = w1s[j - 1];
        if (w < 0.f) {
          float c = w2p[h * RPEn + pidx[j - 1]];
          sn += w * c;
          bn += b1s[j - 1] * c;
        }
      }
    }
  }
}

extern "C" void kernel_launch(void* const* d_in, const int* in_sizes, int n_in,
                              void* d_out, int out_size, void* d_ws, size_t ws_size,
                              hipStream_t stream)
{
  const float* tgt   = (const float*)d_in[0];
  const float* qpos  = (const float*)d_in[1];
  const float* src   = (const float*)d_in[2];
  const float* spe   = (const float*)d_in[3];
  const float* pad   = (const float*)d_in[4];
  const float* rel   = (const float*)d_in[5];
  const float* qw    = (const float*)d_in[6];
  const float* qb    = (const float*)d_in[7];
  const float* kw    = (const float*)d_in[8];
  const float* kb    = (const float*)d_in[9];
  const float* vw    = (const float*)d_in[10];
  const float* vb    = (const float*)d_in[11];
  const float* projw = (const float*)d_in[12];
  const float* projb = (const float*)d_in[13];
  const float* cpbw1 = (const float*)d_in[14];
  const float* cpbb1 = (const float*)d_in[15];
  const float* cpbw2 = (const float*)d_in[16];
  const float* ipw   = (const float*)d_in[17];
  const float* ipb   = (const float*)d_in[18];
  const float* outw  = (const float*)d_in[19];
  const float* outb  = (const float*)d_in[20];
  const float* ln1g  = (const float*)d_in[21];
  const float* ln1b  = (const float*)d_in[22];
  const float* ln2g  = (const float*)d_in[23];
  const float* ln2b  = (const float*)d_in[24];
  const float* ln3g  = (const float*)d_in[25];
  const float* ln3b  = (const float*)d_in[26];
  const float* ff1w  = (const float*)d_in[27];
  const float* ff1b  = (const float*)d_in[28];
  const float* ff2w  = (const float*)d_in[29];
  const float* ff2b  = (const float*)d_in[30];
  float* out = (float*)d_out;
  float* ws = (float*)d_ws;

  constexpr size_t SZ_Q  = (size_t)Bb * NQn * Dn;        // 131072
  constexpr size_t SZ_S  = (size_t)Bb * NSn * Dn;        // 524288
  constexpr size_t SZ_AS = (size_t)Bb * Hn * NQn * NQn;  // 1048576
  constexpr size_t SZ_FFH = (size_t)Bb * NQn * FFNn;     // 524288

  float* qSb  = ws;
  float* kSb  = qSb + SZ_Q;
  float* vSb  = kSb + SZ_Q;
  float* oSb  = vSb + SZ_Q;
  float* soP  = oSb + SZ_Q;
  float* tgt2 = soP + SZ_Q;
  float* qCb  = tgt2 + SZ_Q;
  float* kCb  = qCb + SZ_Q;
  float* vCb  = kCb + SZ_S;
  float* oCb  = vCb + SZ_S;
  float* coP  = oCb + SZ_Q;
  float* tgt3 = coP + SZ_Q;
  float* ffh  = tgt3 + SZ_Q;
  float* ff2o = ffh + SZ_FFH;
  float* tsb  = ff2o + SZ_Q;
  float* Stab = tsb + RPEn;
  float* Btab = Stab + (RPEn + 1) * Hn;
  float* attnS = Btab + (RPEn + 1) * Hn;
  float* attnC = attnS + SZ_AS;

  const int MQ = Bb * NQn;  // 512
  const int MS = Bb * NSn;  // 2048

  // RPE piecewise-linear tables
  build_cpb_tables<<<dim3(1), dim3(RPEn), 0, stream>>>(cpbw1, cpbb1, cpbw2,
                                                       tsb, Stab, Btab);

  // ---- self attention ----
  gemm_kernel<<<dim3(Dn / 64, MQ / 64), 256, 0, stream>>>(
      qSb, tgt, qpos, ipw, ipb, MQ, Dn, Dn, SCALEf, 0);
  gemm_kernel<<<dim3(Dn / 64, MQ / 64), 256, 0, stream>>>(
      kSb, tgt, qpos, ipw + Dn * Dn, ipb + Dn, MQ, Dn, Dn, 1.f, 0);
  gemm_kernel<<<dim3(Dn / 64, MQ / 64), 256, 0, stream>>>(
      vSb, tgt, nullptr, ipw + 2 * Dn * Dn, ipb + 2 * Dn, MQ, Dn, Dn, 1.f, 0);
  logits_kernel<<<dim3(NQn / 64, NQn / 64, Bb * Hn), 256, 0, stream>>>(
      attnS, qSb, kSb, NQn, NQn);
  softmax_kernel<<<dim3(Bb * Hn * NQn), 256, 0, stream>>>(
      attnS, NQn, nullptr, nullptr, nullptr, nullptr, nullptr);
  pv_kernel<<<dim3(NQn / 64, Bb * Hn), 256, 0, stream>>>(
      oSb, attnS, vSb, NQn, NQn);
  gemm_kernel<<<dim3(Dn / 64, MQ / 64), 256, 0, stream>>>(
      soP, oSb, nullptr, outw, outb, MQ, Dn, Dn, 1.f, 0);
  add_ln_kernel<<<dim3(MQ), 256, 0, stream>>>(tgt2, tgt, soP, ln2g, ln2b);

  // ---- cross attention ----
  gemm_kernel<<<dim3(Dn / 64, MQ / 64), 256, 0, stream>>>(
      qCb, tgt2, qpos, qw, qb, MQ, Dn, Dn, SCALEf, 0);
  gemm_kernel<<<dim3(Dn / 64, MS / 64), 256, 0, stream>>>(
      kCb, src, spe, kw, kb, MS, Dn, Dn, 1.f, 0);
  gemm_kernel<<<dim3(Dn / 64, MS / 64), 256, 0, stream>>>(
      vCb, src, nullptr, vw, vb, MS, Dn, Dn, 1.f, 0);
  logits_kernel<<<dim3(NSn / 64, NQn / 64, Bb * Hn), 256, 0, stream>>>(
      attnC, qCb, kCb, NQn, NSn);
  softmax_kernel<<<dim3(Bb * Hn * NQn), 256, 0, stream>>>(
      attnC, NSn, rel, pad, tsb, Stab, Btab);
  pv_kernel<<<dim3(NQn / 64, Bb * Hn), 256, 0, stream>>>(
      oCb, attnC, vCb, NQn, NSn);
  gemm_kernel<<<dim3(Dn / 64, MQ / 64), 256, 0, stream>>>(
      coP, oCb, nullptr, projw, projb, MQ, Dn, Dn, 1.f, 0);
  add_ln_kernel<<<dim3(MQ), 256, 0, stream>>>(tgt3, tgt2, coP, ln1g, ln1b);

  // ---- FFN ----
  gemm_kernel<<<dim3(FFNn / 64, MQ / 64), 256, 0, stream>>>(
      ffh, tgt3, nullptr, ff1w, ff1b, MQ, FFNn, Dn, 1.f, 1);
  gemm_kernel<<<dim3(Dn / 64, MQ / 64), 256, 0, stream>>>(
      ff2o, ffh, nullptr, ff2w, ff2b, MQ, Dn, FFNn, 1.f, 0);
  add_ln_kernel<<<dim3(MQ), 256, 0, stream>>>(out, tgt3, ff2o, ln3g, ln3b);
}

// Round 2
// 458.414 us; speedup vs baseline: 1.6684x; 1.6684x over previous
//
#include <hip/hip_runtime.h>
#include <hip/hip_bf16.h>
#include <math.h>

#define Bb 2
#define NQn 256
#define NSn 1024
#define Dn 256
#define Hn 8
#define DHn 32
#define FFNn 1024
#define RPEn 512
#define SCALEf 0.17677669529663687f
#define EPSf 1e-5f

// ---------------------------------------------------------------------------
// Generic tiled f32 GEMM: C[M,N] = act( (A(+A2)) @ W^T + bias ) * scale
// W is row-major [N,K] (torch-style). 64x64 tile, 256 threads, 4x4 per thread.
// ---------------------------------------------------------------------------
__global__ __launch_bounds__(256) void gemm_kernel(
    float* __restrict__ C, const float* __restrict__ A, const float* __restrict__ A2,
    const float* __restrict__ W, const float* __restrict__ bias,
    int M, int N, int K, float scale, int do_relu)
{
  __shared__ float As[64][17];
  __shared__ float Ws[64][17];
  const int bm = blockIdx.y * 64;
  const int bn = blockIdx.x * 64;
  const int tid = threadIdx.x;
  const int tx = tid & 15, ty = tid >> 4;
  float acc[4][4];
#pragma unroll
  for (int i = 0; i < 4; ++i)
#pragma unroll
    for (int j = 0; j < 4; ++j) acc[i][j] = 0.f;

  for (int k0 = 0; k0 < K; k0 += 16) {
#pragma unroll
    for (int u = 0; u < 4; ++u) {
      int t = tid + u * 256;
      int m = t >> 4, k = t & 15;
      size_t ga = (size_t)(bm + m) * K + k0 + k;
      float v = A[ga];
      if (A2) v += A2[ga];
      As[m][k] = v;
      Ws[m][k] = W[(size_t)(bn + m) * K + k0 + k];
    }
    __syncthreads();
#pragma unroll
    for (int k = 0; k < 16; ++k) {
      float a[4], w[4];
#pragma unroll
      for (int i = 0; i < 4; ++i) a[i] = As[ty * 4 + i][k];
#pragma unroll
      for (int j = 0; j < 4; ++j) w[j] = Ws[tx * 4 + j][k];
#pragma unroll
      for (int i = 0; i < 4; ++i)
#pragma unroll
        for (int j = 0; j < 4; ++j) acc[i][j] += a[i] * w[j];
    }
    __syncthreads();
  }

#pragma unroll
  for (int i = 0; i < 4; ++i) {
    int m = bm + ty * 4 + i;
#pragma unroll
    for (int j = 0; j < 4; ++j) {
      int n = bn + tx * 4 + j;
      float v = acc[i][j];
      if (bias) v += bias[n];
      v *= scale;
      if (do_relu) v = fmaxf(v, 0.f);
      C[(size_t)m * N + n] = v;
    }
  }
}

// ---------------------------------------------------------------------------
// Fused self-attn QKV GEMM. W=ipw [3D, D]. grid: (12, M/64).
// sections: blockIdx.x 0-3 -> q (A+A2, *SCALE), 4-7 -> k (A+A2), 8-11 -> v (A).
// ---------------------------------------------------------------------------
__global__ __launch_bounds__(256) void qkv_self_kernel(
    float* __restrict__ qo, float* __restrict__ ko, float* __restrict__ vo,
    const float* __restrict__ A, const float* __restrict__ A2,
    const float* __restrict__ W, const float* __restrict__ bias)
{
  __shared__ float As[64][17];
  __shared__ float Ws[64][17];
  const int bm = blockIdx.y * 64;
  const int bn = blockIdx.x * 64;
  const int sec = blockIdx.x >> 2;
  const bool addA2 = (sec < 2);
  const float scale = (sec == 0) ? SCALEf : 1.f;
  float* C = (sec == 0) ? qo : (sec == 1) ? ko : vo;
  const int tid = threadIdx.x;
  const int tx = tid & 15, ty = tid >> 4;
  float acc[4][4] = {};

  for (int k0 = 0; k0 < Dn; k0 += 16) {
#pragma unroll
    for (int u = 0; u < 4; ++u) {
      int t = tid + u * 256;
      int m = t >> 4, k = t & 15;
      size_t ga = (size_t)(bm + m) * Dn + k0 + k;
      float v = A[ga];
      if (addA2) v += A2[ga];
      As[m][k] = v;
      Ws[m][k] = W[(size_t)(bn + m) * Dn + k0 + k];
    }
    __syncthreads();
#pragma unroll
    for (int k = 0; k < 16; ++k) {
      float a[4], w[4];
#pragma unroll
      for (int i = 0; i < 4; ++i) a[i] = As[ty * 4 + i][k];
#pragma unroll
      for (int j = 0; j < 4; ++j) w[j] = Ws[tx * 4 + j][k];
#pragma unroll
      for (int i = 0; i < 4; ++i)
#pragma unroll
        for (int j = 0; j < 4; ++j) acc[i][j] += a[i] * w[j];
    }
    __syncthreads();
  }

#pragma unroll
  for (int i = 0; i < 4; ++i) {
    int m = bm + ty * 4 + i;
#pragma unroll
    for (int j = 0; j < 4; ++j) {
      int n = bn + tx * 4 + j;
      float v = (acc[i][j] + bias[n]) * scale;
      C[(size_t)m * Dn + (n & (Dn - 1))] = v;
    }
  }
}

// ---------------------------------------------------------------------------
// Fused cross-attn K/V GEMM. grid: (8, M/64).
// sections: blockIdx.x 0-3 -> k (src+spe, kw), 4-7 -> v (src, vw).
// ---------------------------------------------------------------------------
__global__ __launch_bounds__(256) void kv_cross_kernel(
    float* __restrict__ ko, float* __restrict__ vo,
    const float* __restrict__ src, const float* __restrict__ spe,
    const float* __restrict__ kw, const float* __restrict__ kb,
    const float* __restrict__ vw, const float* __restrict__ vb)
{
  __shared__ float As[64][17];
  __shared__ float Ws[64][17];
  const int bm = blockIdx.y * 64;
  const int bn = blockIdx.x * 64;
  const int sec = blockIdx.x >> 2;
  const float* W = sec ? vw : kw;
  const float* bias = sec ? vb : kb;
  float* C = sec ? vo : ko;
  const int wn0 = bn & (Dn - 1);
  const int tid = threadIdx.x;
  const int tx = tid & 15, ty = tid >> 4;
  float acc[4][4] = {};

  for (int k0 = 0; k0 < Dn; k0 += 16) {
#pragma unroll
    for (int u = 0; u < 4; ++u) {
      int t = tid + u * 256;
      int m = t >> 4, k = t & 15;
      size_t ga = (size_t)(bm + m) * Dn + k0 + k;
      float v = src[ga];
      if (sec == 0) v += spe[ga];
      As[m][k] = v;
      Ws[m][k] = W[(size_t)(wn0 + m) * Dn + k0 + k];
    }
    __syncthreads();
#pragma unroll
    for (int k = 0; k < 16; ++k) {
      float a[4], w[4];
#pragma unroll
      for (int i = 0; i < 4; ++i) a[i] = As[ty * 4 + i][k];
#pragma unroll
      for (int j = 0; j < 4; ++j) w[j] = Ws[tx * 4 + j][k];
#pragma unroll
      for (int i = 0; i < 4; ++i)
#pragma unroll
        for (int j = 0; j < 4; ++j) acc[i][j] += a[i] * w[j];
    }
    __syncthreads();
  }

#pragma unroll
  for (int i = 0; i < 4; ++i) {
    int m = bm + ty * 4 + i;
#pragma unroll
    for (int j = 0; j < 4; ++j) {
      int n = wn0 + tx * 4 + j;
      C[(size_t)m * Dn + n] = acc[i][j] + bias[n];
    }
  }
}

// ---------------------------------------------------------------------------
// Batched attention logits: S[b,h,q,k] = sum_dh Q[b,q,h*32+dh] * K[b,k,h*32+dh]
// grid: (NK/64, NQ/64, B*H)
// ---------------------------------------------------------------------------
__global__ __launch_bounds__(256) void logits_kernel(
    float* __restrict__ S, const float* __restrict__ Q, const float* __restrict__ Km,
    int NQr, int NKr)
{
  __shared__ float Qs[64][33];
  __shared__ float Ks[64][33];
  const int bh = blockIdx.z;
  const int b = bh >> 3, h = bh & 7;
  const int q0 = blockIdx.y * 64, k0 = blockIdx.x * 64;
  const int tid = threadIdx.x;
#pragma unroll
  for (int u = 0; u < 8; ++u) {
    int t = tid + u * 256;
    int r = t >> 5, c = t & 31;
    Qs[r][c] = Q[((size_t)(b * NQr + q0 + r)) * Dn + h * DHn + c];
    Ks[r][c] = Km[((size_t)(b * NKr + k0 + r)) * Dn + h * DHn + c];
  }
  __syncthreads();
  const int tx = tid & 15, ty = tid >> 4;
  float acc[4][4] = {};
#pragma unroll
  for (int d = 0; d < 32; ++d) {
    float a[4], w[4];
#pragma unroll
    for (int i = 0; i < 4; ++i) a[i] = Qs[ty * 4 + i][d];
#pragma unroll
    for (int j = 0; j < 4; ++j) w[j] = Ks[tx * 4 + j][d];
#pragma unroll
    for (int i = 0; i < 4; ++i)
#pragma unroll
      for (int j = 0; j < 4; ++j) acc[i][j] += a[i] * w[j];
  }
#pragma unroll
  for (int i = 0; i < 4; ++i) {
    int q = q0 + ty * 4 + i;
#pragma unroll
    for (int j = 0; j < 4; ++j) {
      int k = k0 + tx * 4 + j;
      S[((size_t)bh * NQr + q) * NKr + k] = acc[i][j];
    }
  }
}

// ---------------------------------------------------------------------------
// Softmax over rows of S (length NKr), optionally adding the piecewise-linear
// RPE bias (binary search in sorted breakpoints) and -100*pad_mask.
// grid: B*H*NQ blocks of 256.
// ---------------------------------------------------------------------------
__global__ __launch_bounds__(256) void softmax_kernel(
    float* __restrict__ S, int NKr,
    const float* __restrict__ rel, const float* __restrict__ pad,
    const float* __restrict__ tsg, const float* __restrict__ Stab,
    const float* __restrict__ Btab)
{
  const int row = blockIdx.x;
  const int q = row & (NQn - 1);
  const int bh = row >> 8;
  const int h = bh & 7, b = bh >> 3;
  float* Srow = S + (size_t)row * NKr;

  __shared__ float ts[RPEn];
  __shared__ float Sh[RPEn + 1];
  __shared__ float Bh[RPEn + 1];
  __shared__ float red[8];

  const bool use_bias = (rel != nullptr);
  if (use_bias) {
    for (int i = threadIdx.x; i < RPEn; i += 256) ts[i] = tsg[i];
    for (int i = threadIdx.x; i < RPEn + 1; i += 256) {
      Sh[i] = Stab[i * Hn + h];
      Bh[i] = Btab[i * Hn + h];
    }
    __syncthreads();
  }

  float vals[4];
  const int nper = NKr >> 8;  // 1 (self) or 4 (cross)
  float mymax = -3.0e38f;
  for (int it = 0; it < nper; ++it) {
    int k = threadIdx.x + (it << 8);
    float v = Srow[k];
    if (use_bias) {
      float m = rel[((size_t)b * NQn + q) * NKr + k];
      int lo = 0, hi = RPEn;
      while (lo < hi) {
        int mid = (lo + hi) >> 1;
        if (ts[mid] < m) lo = mid + 1; else hi = mid;
      }
      v += Sh[lo] * m + Bh[lo];
      v += pad[b * NKr + k] * -100.0f;
    }
    vals[it] = v;
    mymax = fmaxf(mymax, v);
  }

  float wm = mymax;
#pragma unroll
  for (int off = 32; off > 0; off >>= 1) wm = fmaxf(wm, __shfl_down(wm, off));
  const int lane = threadIdx.x & 63, wid = threadIdx.x >> 6;
  if (lane == 0) red[wid] = wm;
  __syncthreads();
  if (threadIdx.x == 0) red[4] = fmaxf(fmaxf(red[0], red[1]), fmaxf(red[2], red[3]));
  __syncthreads();
  const float rowmax = red[4];

  float wsum = 0.f;
  for (int it = 0; it < nper; ++it) {
    vals[it] = __expf(vals[it] - rowmax);
    wsum += vals[it];
  }
#pragma unroll
  for (int off = 32; off > 0; off >>= 1) wsum += __shfl_down(wsum, off);
  if (lane == 0) red[wid] = wsum;
  __syncthreads();
  if (threadIdx.x == 0) red[5] = red[0] + red[1] + red[2] + red[3];
  __syncthreads();
  const float inv = 1.f / red[5];
  for (int it = 0; it < nper; ++it) {
    int k = threadIdx.x + (it << 8);
    Srow[k] = vals[it] * inv;
  }
}

// ---------------------------------------------------------------------------
// PV: O[b,q,h*32+dh] = sum_k P[b,h,q,k] * V[b,k,h*32+dh]
// grid: (NQ/64, B*H)
// ---------------------------------------------------------------------------
__global__ __launch_bounds__(256) void pv_kernel(
    float* __restrict__ O, const float* __restrict__ P, const float* __restrict__ V,
    int NQr, int NKr)
{
  __shared__ float Ps[64][33];
  __shared__ float Vs[32][33];
  const int bh = blockIdx.y;
  const int b = bh >> 3, h = bh & 7;
  const int q0 = blockIdx.x * 64;
  const int tid = threadIdx.x;
  const int dh = tid & 31, tq = tid >> 5;
  float acc[8] = {};
  for (int k0 = 0; k0 < NKr; k0 += 32) {
#pragma unroll
    for (int u = 0; u < 8; ++u) {
      int t = tid + u * 256;
      int r = t >> 5, c = t & 31;
      Ps[r][c] = P[((size_t)bh * NQr + q0 + r) * NKr + k0 + c];
    }
#pragma unroll
    for (int u = 0; u < 4; ++u) {
      int t = tid + u * 256;
      int r = t >> 5, c = t & 31;
      Vs[r][c] = V[((size_t)(b * NKr + k0 + r)) * Dn + h * DHn + c];
    }
    __syncthreads();
#pragma unroll
    for (int kk = 0; kk < 32; ++kk) {
      float vv = Vs[kk][dh];
#pragma unroll
      for (int i = 0; i < 8; ++i) acc[i] += Ps[tq * 8 + i][kk] * vv;
    }
    __syncthreads();
  }
#pragma unroll
  for (int i = 0; i < 8; ++i)
    O[((size_t)(b * NQr + q0 + tq * 8 + i)) * Dn + h * DHn + dh] = acc[i];
}

// ---------------------------------------------------------------------------
// out = LayerNorm(x1 + x2) * g + b.  grid: B*NQ rows, block = 256 = D.
// ---------------------------------------------------------------------------
__global__ __launch_bounds__(256) void add_ln_kernel(
    float* __restrict__ out, const float* __restrict__ x1, const float* __restrict__ x2,
    const float* __restrict__ g, const float* __restrict__ bt)
{
  const int row = blockIdx.x;
  const int t = threadIdx.x;
  const float v = x1[(size_t)row * Dn + t] + x2[(size_t)row * Dn + t];
  float s = v, s2 = v * v;
#pragma unroll
  for (int off = 32; off > 0; off >>= 1) {
    s += __shfl_down(s, off);
    s2 += __shfl_down(s2, off);
  }
  __shared__ float rs[4], rs2[4], fin[2];
  const int lane = t & 63, wid = t >> 6;
  if (lane == 0) { rs[wid] = s; rs2[wid] = s2; }
  __syncthreads();
  if (t == 0) {
    float a = rs[0] + rs[1] + rs[2] + rs[3];
    float a2 = rs2[0] + rs2[1] + rs2[2] + rs2[3];
    float mean = a * (1.f / Dn);
    float var = a2 * (1.f / Dn) - mean * mean;
    fin[0] = mean;
    fin[1] = rsqrtf(var + EPSf);
  }
  __syncthreads();
  out[(size_t)row * Dn + t] = (v - fin[0]) * fin[1] * g[t] + bt[t];
}

// ---------------------------------------------------------------------------
// Build piecewise-linear tables for the RPE bias:
//   bias_h(m) = Stot[j][h]*m + Btot[j][h],  j = #{ t_sorted < m }
// One block, 512 threads. Bitonic sort, then PARALLEL per-head prefix sums:
// one wave per head, 8 elements per lane, shfl-scan of chunk totals.
// suffix_incl[j] = total - prefix_excl[j] turns the backward pass into the
// same forward exclusive scan.
// ---------------------------------------------------------------------------
__global__ __launch_bounds__(512) void build_cpb_tables(
    const float* __restrict__ w1p, const float* __restrict__ b1p,
    const float* __restrict__ w2p,
    float* __restrict__ tout, float* __restrict__ Stab, float* __restrict__ Btab)
{
  __shared__ float key[RPEn];
  __shared__ int pidx[RPEn];
  __shared__ float w1s[RPEn];
  __shared__ float b1s[RPEn];
  const int tid = threadIdx.x;
  {
    float w = w1p[tid], bb = b1p[tid];
    key[tid] = (w != 0.f) ? (-bb / w) : 3.0e38f;
    pidx[tid] = tid;
  }
  __syncthreads();
  for (int k = 2; k <= RPEn; k <<= 1) {
    for (int j = k >> 1; j > 0; j >>= 1) {
      int ixj = tid ^ j;
      if (ixj > tid) {
        float a = key[tid], c = key[ixj];
        bool asc = ((tid & k) == 0);
        bool sw = asc ? (a > c) : (a < c);
        if (sw) {
          key[tid] = c; key[ixj] = a;
          int tmp = pidx[tid]; pidx[tid] = pidx[ixj]; pidx[ixj] = tmp;
        }
      }
      __syncthreads();
    }
  }
  w1s[tid] = w1p[pidx[tid]];
  b1s[tid] = b1p[pidx[tid]];
  tout[tid] = key[tid];
  __syncthreads();

  // one wave per head
  const int lane = tid & 63;
  const int h = tid >> 6;
  const int j0 = lane * 8;
  float sp[8], bp[8], sn[8], bn[8];
  float csp = 0.f, cbp = 0.f, csn = 0.f, cbn = 0.f, ccc = 0.f;
#pragma unroll
  for (int e = 0; e < 8; ++e) {
    int j = j0 + e;
    float w = w1s[j], b = b1s[j];
    float c = w2p[h * RPEn + pidx[j]];
    sp[e] = csp; bp[e] = cbp; sn[e] = csn; bn[e] = cbn;  // within-chunk exclusive
    if (w > 0.f)      { csp += w * c; cbp += b * c; }
    else if (w < 0.f) { csn += w * c; cbn += b * c; }
    else              { ccc += fmaxf(b, 0.f) * c; }
  }
  // wave inclusive scan of chunk totals + butterfly reduce of ccc
  float isp = csp, ibp = cbp, isn = csn, ibn = cbn, icc = ccc;
#pragma unroll
  for (int d = 1; d < 64; d <<= 1) {
    float t0 = __shfl_up(isp, d);
    float t1 = __shfl_up(ibp, d);
    float t2 = __shfl_up(isn, d);
    float t3 = __shfl_up(ibn, d);
    if (lane >= d) { isp += t0; ibp += t1; isn += t2; ibn += t3; }
    icc += __shfl_xor(icc, d);
  }
  const float tsn = __shfl(isn, 63);
  const float tbn = __shfl(ibn, 63);
  const float esp = isp - csp;  // exclusive chunk-prefix for this lane
  const float ebp = ibp - cbp;
  const float esn = isn - csn;
  const float ebn = ibn - cbn;
#pragma unroll
  for (int e = 0; e < 8; ++e) {
    int j = j0 + e;
    Stab[j * Hn + h] = (esp + sp[e]) + (tsn - (esn + sn[e]));
    Btab[j * Hn + h] = (ebp + bp[e]) + (tbn - (ebn + bn[e])) + icc;
  }
  if (lane == 63) {
    Stab[RPEn * Hn + h] = isp;
    Btab[RPEn * Hn + h] = ibp + icc;
  }
}

extern "C" void kernel_launch(void* const* d_in, const int* in_sizes, int n_in,
                              void* d_out, int out_size, void* d_ws, size_t ws_size,
                              hipStream_t stream)
{
  const float* tgt   = (const float*)d_in[0];
  const float* qpos  = (const float*)d_in[1];
  const float* src   = (const float*)d_in[2];
  const float* spe   = (const float*)d_in[3];
  const float* pad   = (const float*)d_in[4];
  const float* rel   = (const float*)d_in[5];
  const float* qw    = (const float*)d_in[6];
  const float* qb    = (const float*)d_in[7];
  const float* kw    = (const float*)d_in[8];
  const float* kb    = (const float*)d_in[9];
  const float* vw    = (const float*)d_in[10];
  const float* vb    = (const float*)d_in[11];
  const float* projw = (const float*)d_in[12];
  const float* projb = (const float*)d_in[13];
  const float* cpbw1 = (const float*)d_in[14];
  const float* cpbb1 = (const float*)d_in[15];
  const float* cpbw2 = (const float*)d_in[16];
  const float* ipw   = (const float*)d_in[17];
  const float* ipb   = (const float*)d_in[18];
  const float* outw  = (const float*)d_in[19];
  const float* outb  = (const float*)d_in[20];
  const float* ln1g  = (const float*)d_in[21];
  const float* ln1b  = (const float*)d_in[22];
  const float* ln2g  = (const float*)d_in[23];
  const float* ln2b  = (const float*)d_in[24];
  const float* ln3g  = (const float*)d_in[25];
  const float* ln3b  = (const float*)d_in[26];
  const float* ff1w  = (const float*)d_in[27];
  const float* ff1b  = (const float*)d_in[28];
  const float* ff2w  = (const float*)d_in[29];
  const float* ff2b  = (const float*)d_in[30];
  float* out = (float*)d_out;
  float* ws = (float*)d_ws;

  constexpr size_t SZ_Q  = (size_t)Bb * NQn * Dn;        // 131072
  constexpr size_t SZ_S  = (size_t)Bb * NSn * Dn;        // 524288
  constexpr size_t SZ_AS = (size_t)Bb * Hn * NQn * NQn;  // 1048576
  constexpr size_t SZ_FFH = (size_t)Bb * NQn * FFNn;     // 524288

  float* qSb  = ws;
  float* kSb  = qSb + SZ_Q;
  float* vSb  = kSb + SZ_Q;
  float* oSb  = vSb + SZ_Q;
  float* soP  = oSb + SZ_Q;
  float* tgt2 = soP + SZ_Q;
  float* qCb  = tgt2 + SZ_Q;
  float* kCb  = qCb + SZ_Q;
  float* vCb  = kCb + SZ_S;
  float* oCb  = vCb + SZ_S;
  float* coP  = oCb + SZ_Q;
  float* tgt3 = coP + SZ_Q;
  float* ffh  = tgt3 + SZ_Q;
  float* ff2o = ffh + SZ_FFH;
  float* tsb  = ff2o + SZ_Q;
  float* Stab = tsb + RPEn;
  float* Btab = Stab + (RPEn + 1) * Hn;
  float* attnS = Btab + (RPEn + 1) * Hn;
  float* attnC = attnS + SZ_AS;

  const int MQ = Bb * NQn;  // 512
  const int MS = Bb * NSn;  // 2048

  // RPE piecewise-linear tables
  build_cpb_tables<<<dim3(1), dim3(RPEn), 0, stream>>>(cpbw1, cpbb1, cpbw2,
                                                       tsb, Stab, Btab);

  // ---- self attention ----
  qkv_self_kernel<<<dim3(12, MQ / 64), 256, 0, stream>>>(
      qSb, kSb, vSb, tgt, qpos, ipw, ipb);
  logits_kernel<<<dim3(NQn / 64, NQn / 64, Bb * Hn), 256, 0, stream>>>(
      attnS, qSb, kSb, NQn, NQn);
  softmax_kernel<<<dim3(Bb * Hn * NQn), 256, 0, stream>>>(
      attnS, NQn, nullptr, nullptr, nullptr, nullptr, nullptr);
  pv_kernel<<<dim3(NQn / 64, Bb * Hn), 256, 0, stream>>>(
      oSb, attnS, vSb, NQn, NQn);
  gemm_kernel<<<dim3(Dn / 64, MQ / 64), 256, 0, stream>>>(
      soP, oSb, nullptr, outw, outb, MQ, Dn, Dn, 1.f, 0);
  add_ln_kernel<<<dim3(MQ), 256, 0, stream>>>(tgt2, tgt, soP, ln2g, ln2b);

  // ---- cross attention ----
  gemm_kernel<<<dim3(Dn / 64, MQ / 64), 256, 0, stream>>>(
      qCb, tgt2, qpos, qw, qb, MQ, Dn, Dn, SCALEf, 0);
  kv_cross_kernel<<<dim3(8, MS / 64), 256, 0, stream>>>(
      kCb, vCb, src, spe, kw, kb, vw, vb);
  logits_kernel<<<dim3(NSn / 64, NQn / 64, Bb * Hn), 256, 0, stream>>>(
      attnC, qCb, kCb, NQn, NSn);
  softmax_kernel<<<dim3(Bb * Hn * NQn), 256, 0, stream>>>(
      attnC, NSn, rel, pad, tsb, Stab, Btab);
  pv_kernel<<<dim3(NQn / 64, Bb * Hn), 256, 0, stream>>>(
      oCb, attnC, vCb, NQn, NSn);
  gemm_kernel<<<dim3(Dn / 64, MQ / 64), 256, 0, stream>>>(
      coP, oCb, nullptr, projw, projb, MQ, Dn, Dn, 1.f, 0);
  add_ln_kernel<<<dim3(MQ), 256, 0, stream>>>(tgt3, tgt2, coP, ln1g, ln1b);

  // ---- FFN ----
  gemm_kernel<<<dim3(FFNn / 64, MQ / 64), 256, 0, stream>>>(
      ffh, tgt3, nullptr, ff1w, ff1b, MQ, FFNn, Dn, 1.f, 1);
  gemm_kernel<<<dim3(Dn / 64, MQ / 64), 256, 0, stream>>>(
      ff2o, ffh, nullptr, ff2w, ff2b, MQ, Dn, FFNn, 1.f, 0);
  add_ln_kernel<<<dim3(MQ), 256, 0, stream>>>(out, tgt3, ff2o, ln3g, ln3b);
}

// Round 3
// 416.658 us; speedup vs baseline: 1.8356x; 1.1002x over previous
//
#include <hip/hip_runtime.h>
#include <hip/hip_bf16.h>
#include <math.h>

#define Bb 2
#define NQn 256
#define NSn 1024
#define Dn 256
#define Hn 8
#define DHn 32
#define FFNn 1024
#define RPEn 512
#define SCALEf 0.17677669529663687f
#define EPSf 1e-5f

// ---------------------------------------------------------------------------
// gemm64 body: 64x64 tile, 512 threads. thread -> rows {ty, ty+32}, cols tx*4..+3
// C[M,*] row stride ldc; A (+A2) row stride ld; W row-major [*, ld].
// ---------------------------------------------------------------------------
__device__ __forceinline__ void gemm64_body(
    float* __restrict__ C, int ldc,
    const float* __restrict__ A, const float* __restrict__ A2, int ld,
    const float* __restrict__ W, const float* __restrict__ bias,
    int K, int bm, int bnC, int bnW, float scale, int do_relu,
    float (*As)[17], float (*Ws)[17])
{
  const int tid = threadIdx.x;
  const int tx = tid & 15, ty = tid >> 4;  // ty 0..31
  float acc[2][4] = {};
  const int lr = tid >> 3, lc = (tid & 7) * 2;
  for (int k0 = 0; k0 < K; k0 += 16) {
    {
      const float* Ap = A + (size_t)(bm + lr) * ld + k0 + lc;
      float v0 = Ap[0], v1 = Ap[1];
      if (A2) {
        const float* Bp = A2 + (size_t)(bm + lr) * ld + k0 + lc;
        v0 += Bp[0]; v1 += Bp[1];
      }
      As[lr][lc] = v0; As[lr][lc + 1] = v1;
      const float* Wp = W + (size_t)(bnW + lr) * ld + k0 + lc;
      Ws[lr][lc] = Wp[0]; Ws[lr][lc + 1] = Wp[1];
    }
    __syncthreads();
#pragma unroll
    for (int k = 0; k < 16; ++k) {
      float a0 = As[ty][k], a1 = As[ty + 32][k];
      float w0 = Ws[tx * 4 + 0][k], w1 = Ws[tx * 4 + 1][k];
      float w2 = Ws[tx * 4 + 2][k], w3 = Ws[tx * 4 + 3][k];
      acc[0][0] += a0 * w0; acc[0][1] += a0 * w1; acc[0][2] += a0 * w2; acc[0][3] += a0 * w3;
      acc[1][0] += a1 * w0; acc[1][1] += a1 * w1; acc[1][2] += a1 * w2; acc[1][3] += a1 * w3;
    }
    __syncthreads();
  }
#pragma unroll
  for (int i = 0; i < 2; ++i) {
    int m = bm + ty + i * 32;
#pragma unroll
    for (int j = 0; j < 4; ++j) {
      float v = acc[i][j];
      if (bias) v += bias[bnW + tx * 4 + j];
      v *= scale;
      if (do_relu) v = fmaxf(v, 0.f);
      C[(size_t)m * ldc + bnC + tx * 4 + j] = v;
    }
  }
}

// ---------------------------------------------------------------------------
// prep: fused build_cpb (1 block) + self QKV GEMM (96 blocks) + cross KV GEMM
// (256 blocks). 512 threads/block.
// ---------------------------------------------------------------------------
__global__ __launch_bounds__(512) void prep_kernel(
    float* __restrict__ qSb, float* __restrict__ kSb, float* __restrict__ vSb,
    float* __restrict__ kCb, float* __restrict__ vCb,
    const float* __restrict__ tgt, const float* __restrict__ qpos,
    const float* __restrict__ src, const float* __restrict__ spe,
    const float* __restrict__ ipw, const float* __restrict__ ipb,
    const float* __restrict__ kw, const float* __restrict__ kb,
    const float* __restrict__ vw, const float* __restrict__ vb,
    const float* __restrict__ w1p, const float* __restrict__ b1p,
    const float* __restrict__ w2p,
    float* __restrict__ tout, float* __restrict__ Stab, float* __restrict__ Btab)
{
  __shared__ float smem[2176];
  const int bx = blockIdx.x;
  const int tid = threadIdx.x;
  if (bx < 96) {
    float (*As)[17] = (float(*)[17])smem;
    float (*Ws)[17] = (float(*)[17])(smem + 1088);
    int my = bx & 7, nx = bx >> 3;
    int sec = nx >> 2;
    float* C = sec == 0 ? qSb : (sec == 1 ? kSb : vSb);
    gemm64_body(C, Dn, tgt, sec < 2 ? qpos : nullptr, Dn, ipw, ipb,
                Dn, my * 64, (nx & 3) * 64, nx * 64,
                sec == 0 ? SCALEf : 1.f, 0, As, Ws);
    return;
  }
  if (bx < 96 + 256) {
    float (*As)[17] = (float(*)[17])smem;
    float (*Ws)[17] = (float(*)[17])(smem + 1088);
    int idx = bx - 96;
    int my = idx & 31, nx = idx >> 5;
    int sec = nx >> 2;
    gemm64_body(sec ? vCb : kCb, Dn, src, sec ? nullptr : spe, Dn,
                sec ? vw : kw, sec ? vb : kb,
                Dn, my * 64, (nx & 3) * 64, (nx & 3) * 64, 1.f, 0, As, Ws);
    return;
  }
  // ---- cpb piecewise-linear table build (verified in rounds 1-2) ----
  float* key = smem;
  int* pidx = (int*)(smem + 512);
  float* w1s = smem + 1024;
  float* b1s = smem + 1536;
  {
    float w = w1p[tid], bb = b1p[tid];
    key[tid] = (w != 0.f) ? (-bb / w) : 3.0e38f;
    pidx[tid] = tid;
  }
  __syncthreads();
  for (int k = 2; k <= RPEn; k <<= 1) {
    for (int j = k >> 1; j > 0; j >>= 1) {
      int ixj = tid ^ j;
      if (ixj > tid) {
        float a = key[tid], c = key[ixj];
        bool asc = ((tid & k) == 0);
        bool sw = asc ? (a > c) : (a < c);
        if (sw) {
          key[tid] = c; key[ixj] = a;
          int tmp = pidx[tid]; pidx[tid] = pidx[ixj]; pidx[ixj] = tmp;
        }
      }
      __syncthreads();
    }
  }
  w1s[tid] = w1p[pidx[tid]];
  b1s[tid] = b1p[pidx[tid]];
  tout[tid] = key[tid];
  __syncthreads();
  const int lane = tid & 63;
  const int h = tid >> 6;
  const int j0 = lane * 8;
  float sp[8], bp[8], sn[8], bn[8];
  float csp = 0.f, cbp = 0.f, csn = 0.f, cbn = 0.f, ccc = 0.f;
#pragma unroll
  for (int e = 0; e < 8; ++e) {
    int j = j0 + e;
    float w = w1s[j], b = b1s[j];
    float c = w2p[h * RPEn + pidx[j]];
    sp[e] = csp; bp[e] = cbp; sn[e] = csn; bn[e] = cbn;
    if (w > 0.f)      { csp += w * c; cbp += b * c; }
    else if (w < 0.f) { csn += w * c; cbn += b * c; }
    else              { ccc += fmaxf(b, 0.f) * c; }
  }
  float isp = csp, ibp = cbp, isn = csn, ibn = cbn, icc = ccc;
#pragma unroll
  for (int d = 1; d < 64; d <<= 1) {
    float t0 = __shfl_up(isp, d);
    float t1 = __shfl_up(ibp, d);
    float t2 = __shfl_up(isn, d);
    float t3 = __shfl_up(ibn, d);
    if (lane >= d) { isp += t0; ibp += t1; isn += t2; ibn += t3; }
    icc += __shfl_xor(icc, d);
  }
  const float tsn = __shfl(isn, 63);
  const float tbn = __shfl(ibn, 63);
  const float esp = isp - csp, ebp = ibp - cbp;
  const float esn = isn - csn, ebn = ibn - cbn;
#pragma unroll
  for (int e = 0; e < 8; ++e) {
    int j = j0 + e;
    Stab[j * Hn + h] = (esp + sp[e]) + (tsn - (esn + sn[e]));
    Btab[j * Hn + h] = (ebp + bp[e]) + (tbn - (ebn + bn[e])) + icc;
  }
  if (lane == 63) {
    Stab[RPEn * Hn + h] = isp;
    Btab[RPEn * Hn + h] = ibp + icc;
  }
}

// ---------------------------------------------------------------------------
// gemm64 standalone (FFN1): grid (N/64, M/64), 512 threads.
// ---------------------------------------------------------------------------
__global__ __launch_bounds__(512) void gemm64_kernel(
    float* __restrict__ C, const float* __restrict__ A,
    const float* __restrict__ W, const float* __restrict__ bias,
    int ld, int ldc, int do_relu)
{
  __shared__ float smem[2176];
  float (*As)[17] = (float(*)[17])smem;
  float (*Ws)[17] = (float(*)[17])(smem + 1088);
  gemm64_body(C, ldc, A, nullptr, ld, W, bias, ld,
              blockIdx.y * 64, blockIdx.x * 64, blockIdx.x * 64, 1.f, do_relu,
              As, Ws);
}

// ---------------------------------------------------------------------------
// gemm32: 32x32 tile, 256 threads, 2x2/thread, K-step 32, float4 staging.
// Supports split-K via blockIdx.z (writes partials at kz*M*N).
// ---------------------------------------------------------------------------
__global__ __launch_bounds__(256) void gemm32_kernel(
    float* __restrict__ C, const float* __restrict__ A, const float* __restrict__ A2,
    const float* __restrict__ W, const float* __restrict__ bias,
    int N, int Kchunk, int Ktot, float scale)
{
  __shared__ float As[32][33];
  __shared__ float Ws[32][33];
  const int bm = blockIdx.y * 32, bn = blockIdx.x * 32;
  const int kz = blockIdx.z;
  const int M = gridDim.y * 32;
  float* Cp = C + (size_t)kz * M * N;
  const int tid = threadIdx.x;
  const int tx = tid & 15, ty = tid >> 4;
  const int lr = tid >> 3, lc = (tid & 7) * 4;
  float acc[2][2] = {};
  const int k00 = kz * Kchunk;
  for (int k0 = k00; k0 < k00 + Kchunk; k0 += 32) {
    float4 av = *(const float4*)(A + (size_t)(bm + lr) * Ktot + k0 + lc);
    if (A2) {
      float4 bv = *(const float4*)(A2 + (size_t)(bm + lr) * Ktot + k0 + lc);
      av.x += bv.x; av.y += bv.y; av.z += bv.z; av.w += bv.w;
    }
    As[lr][lc] = av.x; As[lr][lc + 1] = av.y; As[lr][lc + 2] = av.z; As[lr][lc + 3] = av.w;
    float4 wv = *(const float4*)(W + (size_t)(bn + lr) * Ktot + k0 + lc);
    Ws[lr][lc] = wv.x; Ws[lr][lc + 1] = wv.y; Ws[lr][lc + 2] = wv.z; Ws[lr][lc + 3] = wv.w;
    __syncthreads();
#pragma unroll
    for (int k = 0; k < 32; ++k) {
      float a0 = As[ty * 2][k], a1 = As[ty * 2 + 1][k];
      float w0 = Ws[tx * 2][k], w1 = Ws[tx * 2 + 1][k];
      acc[0][0] += a0 * w0; acc[0][1] += a0 * w1;
      acc[1][0] += a1 * w0; acc[1][1] += a1 * w1;
    }
    __syncthreads();
  }
#pragma unroll
  for (int i = 0; i < 2; ++i) {
    int m = bm + ty * 2 + i;
#pragma unroll
    for (int j = 0; j < 2; ++j) {
      int n = bn + tx * 2 + j;
      float v = acc[i][j];
      if (bias) v += bias[n];
      Cp[(size_t)m * N + n] = v * scale;
    }
  }
}

// ---------------------------------------------------------------------------
// Flash self-attention: fused logits+softmax+PV. grid (NQ/16, B*H), 256 thr.
// K/V staged in LDS as float4 with XOR swizzle (d4 ^ (k&7)).
// thread -> (q-row r = tid>>4, k-slice kc = tid&15).
// ---------------------------------------------------------------------------
__global__ __launch_bounds__(256) void flash_self(
    float* __restrict__ O, const float* __restrict__ Q,
    const float* __restrict__ K, const float* __restrict__ V)
{
  __shared__ float4 Ks[2048];
  __shared__ float4 Vs[2048];
  __shared__ float4 Qs[128];
  const int bh = blockIdx.y, b = bh >> 3, h = bh & 7;
  const int q0 = blockIdx.x * 16;
  const int tid = threadIdx.x;
  const float4* Kg = (const float4*)K;
  const float4* Vg = (const float4*)V;
#pragma unroll
  for (int u = 0; u < 8; ++u) {
    int e = tid + u * 256;
    int k = e >> 3, d4 = e & 7;
    int sw = (k << 3) | (d4 ^ (k & 7));
    Ks[sw] = Kg[(size_t)(b * NQn + k) * 64 + h * 8 + d4];
    Vs[sw] = Vg[(size_t)(b * NQn + k) * 64 + h * 8 + d4];
  }
  if (tid < 128) {
    int rr = tid >> 3, d4 = tid & 7;
    Qs[tid] = ((const float4*)Q)[(size_t)(b * NQn + q0 + rr) * 64 + h * 8 + d4];
  }
  __syncthreads();
  const int r = tid >> 4, kc = tid & 15;
  float4 q[8];
#pragma unroll
  for (int d4 = 0; d4 < 8; ++d4) q[d4] = Qs[r * 8 + d4];
  float s[16];
#pragma unroll
  for (int j = 0; j < 16; ++j) {
    int k = kc + j * 16;
    float4 a4 = {0.f, 0.f, 0.f, 0.f};
#pragma unroll
    for (int d4 = 0; d4 < 8; ++d4) {
      float4 kk = Ks[(k << 3) | (d4 ^ (k & 7))];
      a4.x += q[d4].x * kk.x; a4.y += q[d4].y * kk.y;
      a4.z += q[d4].z * kk.z; a4.w += q[d4].w * kk.w;
    }
    s[j] = (a4.x + a4.y) + (a4.z + a4.w);
  }
  float mx = s[0];
#pragma unroll
  for (int j = 1; j < 16; ++j) mx = fmaxf(mx, s[j]);
#pragma unroll
  for (int off = 1; off < 16; off <<= 1) mx = fmaxf(mx, __shfl_xor(mx, off));
  float l = 0.f;
#pragma unroll
  for (int j = 0; j < 16; ++j) { s[j] = __expf(s[j] - mx); l += s[j]; }
#pragma unroll
  for (int off = 1; off < 16; off <<= 1) l += __shfl_xor(l, off);
  float4 o[8] = {};
#pragma unroll
  for (int j = 0; j < 16; ++j) {
    int k = kc + j * 16;
    float p = s[j];
#pragma unroll
    for (int d4 = 0; d4 < 8; ++d4) {
      float4 vv = Vs[(k << 3) | (d4 ^ (k & 7))];
      o[d4].x += p * vv.x; o[d4].y += p * vv.y;
      o[d4].z += p * vv.z; o[d4].w += p * vv.w;
    }
  }
#pragma unroll
  for (int off = 1; off < 16; off <<= 1) {
#pragma unroll
    for (int d4 = 0; d4 < 8; ++d4) {
      o[d4].x += __shfl_xor(o[d4].x, off);
      o[d4].y += __shfl_xor(o[d4].y, off);
      o[d4].z += __shfl_xor(o[d4].z, off);
      o[d4].w += __shfl_xor(o[d4].w, off);
    }
  }
  if (kc == 0) {
    float inv = 1.f / l;
#pragma unroll
    for (int d4 = 0; d4 < 8; ++d4) {
      float4 w = o[d4];
      w.x *= inv; w.y *= inv; w.z *= inv; w.w *= inv;
      ((float4*)O)[(size_t)(b * NQn + q0 + r) * 64 + h * 8 + d4] = w;
    }
  }
}

// ---------------------------------------------------------------------------
// Flash cross-attention with RPE piecewise-linear bias + padding mask.
// grid (NQ/16, B*H), 256 threads; online softmax over 4 chunks of 256 keys.
// ---------------------------------------------------------------------------
__global__ __launch_bounds__(256) void flash_cross(
    float* __restrict__ O, const float* __restrict__ Q,
    const float* __restrict__ K, const float* __restrict__ V,
    const float* __restrict__ rel, const float* __restrict__ pad,
    const float* __restrict__ tsg, const float* __restrict__ Stabg,
    const float* __restrict__ Btabg)
{
  __shared__ float4 Ks[2048];
  __shared__ float4 Vs[2048];
  __shared__ float4 Qs[128];
  __shared__ float ts[RPEn];
  __shared__ float Sh[RPEn + 1];
  __shared__ float Bh[RPEn + 1];
  __shared__ float pads[256];
  const int bh = blockIdx.y, b = bh >> 3, h = bh & 7;
  const int q0 = blockIdx.x * 16;
  const int tid = threadIdx.x;
  for (int i = tid; i < RPEn; i += 256) ts[i] = tsg[i];
  for (int i = tid; i < RPEn + 1; i += 256) {
    Sh[i] = Stabg[i * Hn + h];
    Bh[i] = Btabg[i * Hn + h];
  }
  if (tid < 128) {
    int rr = tid >> 3, d4 = tid & 7;
    Qs[tid] = ((const float4*)Q)[(size_t)(b * NQn + q0 + rr) * 64 + h * 8 + d4];
  }
  __syncthreads();
  const int r = tid >> 4, kc = tid & 15;
  const int qrow = b * NQn + q0 + r;
  float4 q[8];
#pragma unroll
  for (int d4 = 0; d4 < 8; ++d4) q[d4] = Qs[r * 8 + d4];
  float4 o[8] = {};
  float m_run = -3.0e38f, l_run = 0.f;
  const float4* Kg = (const float4*)K;
  const float4* Vg = (const float4*)V;
  for (int c = 0; c < 4; ++c) {
    const int kb0 = c * 256;
#pragma unroll
    for (int u = 0; u < 8; ++u) {
      int e = tid + u * 256;
      int k = e >> 3, d4 = e & 7;
      int sw = (k << 3) | (d4 ^ (k & 7));
      Ks[sw] = Kg[(size_t)(b * NSn + kb0 + k) * 64 + h * 8 + d4];
      Vs[sw] = Vg[(size_t)(b * NSn + kb0 + k) * 64 + h * 8 + d4];
    }
    pads[tid] = pad[b * NSn + kb0 + tid];
    __syncthreads();
    float s[16];
    float cmax = -3.0e38f;
#pragma unroll
    for (int j = 0; j < 16; ++j) {
      int k = kc + j * 16;
      float4 a4 = {0.f, 0.f, 0.f, 0.f};
#pragma unroll
      for (int d4 = 0; d4 < 8; ++d4) {
        float4 kk = Ks[(k << 3) | (d4 ^ (k & 7))];
        a4.x += q[d4].x * kk.x; a4.y += q[d4].y * kk.y;
        a4.z += q[d4].z * kk.z; a4.w += q[d4].w * kk.w;
      }
      float sv = (a4.x + a4.y) + (a4.z + a4.w);
      float mrel = rel[(size_t)qrow * NSn + kb0 + k];
      int lo = 0, hi = RPEn;
      while (lo < hi) {
        int mid = (lo + hi) >> 1;
        if (ts[mid] < mrel) lo = mid + 1; else hi = mid;
      }
      sv += Sh[lo] * mrel + Bh[lo];
      sv -= 100.f * pads[k];
      s[j] = sv;
      cmax = fmaxf(cmax, sv);
    }
#pragma unroll
    for (int off = 1; off < 16; off <<= 1) cmax = fmaxf(cmax, __shfl_xor(cmax, off));
    float m_new = fmaxf(m_run, cmax);
    float f = __expf(m_run - m_new);
    float lsum = 0.f;
#pragma unroll
    for (int j = 0; j < 16; ++j) { s[j] = __expf(s[j] - m_new); lsum += s[j]; }
#pragma unroll
    for (int off = 1; off < 16; off <<= 1) lsum += __shfl_xor(lsum, off);
    l_run = l_run * f + lsum;
    m_run = m_new;
#pragma unroll
    for (int d4 = 0; d4 < 8; ++d4) {
      o[d4].x *= f; o[d4].y *= f; o[d4].z *= f; o[d4].w *= f;
    }
#pragma unroll
    for (int j = 0; j < 16; ++j) {
      int k = kc + j * 16;
      float p = s[j];
#pragma unroll
      for (int d4 = 0; d4 < 8; ++d4) {
        float4 vv = Vs[(k << 3) | (d4 ^ (k & 7))];
        o[d4].x += p * vv.x; o[d4].y += p * vv.y;
        o[d4].z += p * vv.z; o[d4].w += p * vv.w;
      }
    }
    __syncthreads();
  }
#pragma unroll
  for (int off = 1; off < 16; off <<= 1) {
#pragma unroll
    for (int d4 = 0; d4 < 8; ++d4) {
      o[d4].x += __shfl_xor(o[d4].x, off);
      o[d4].y += __shfl_xor(o[d4].y, off);
      o[d4].z += __shfl_xor(o[d4].z, off);
      o[d4].w += __shfl_xor(o[d4].w, off);
    }
  }
  if (kc == 0) {
    float inv = 1.f / l_run;
#pragma unroll
    for (int d4 = 0; d4 < 8; ++d4) {
      float4 w = o[d4];
      w.x *= inv; w.y *= inv; w.z *= inv; w.w *= inv;
      ((float4*)O)[(size_t)qrow * 64 + h * 8 + d4] = w;
    }
  }
}

// ---------------------------------------------------------------------------
// out = LayerNorm(x1 + x2) * g + b.  grid: rows, block = 256 = D.
// ---------------------------------------------------------------------------
__global__ __launch_bounds__(256) void add_ln_kernel(
    float* __restrict__ out, const float* __restrict__ x1, const float* __restrict__ x2,
    const float* __restrict__ g, const float* __restrict__ bt)
{
  const int row = blockIdx.x;
  const int t = threadIdx.x;
  const float v = x1[(size_t)row * Dn + t] + x2[(size_t)row * Dn + t];
  float s = v, s2 = v * v;
#pragma unroll
  for (int off = 32; off > 0; off >>= 1) {
    s += __shfl_down(s, off);
    s2 += __shfl_down(s2, off);
  }
  __shared__ float rs[4], rs2[4], fin[2];
  const int lane = t & 63, wid = t >> 6;
  if (lane == 0) { rs[wid] = s; rs2[wid] = s2; }
  __syncthreads();
  if (t == 0) {
    float a = rs[0] + rs[1] + rs[2] + rs[3];
    float a2 = rs2[0] + rs2[1] + rs2[2] + rs2[3];
    float mean = a * (1.f / Dn);
    float var = a2 * (1.f / Dn) - mean * mean;
    fin[0] = mean;
    fin[1] = rsqrtf(var + EPSf);
  }
  __syncthreads();
  out[(size_t)row * Dn + t] = (v - fin[0]) * fin[1] * g[t] + bt[t];
}

// ---------------------------------------------------------------------------
// out = LayerNorm(resid + sum_{kz<4} part[kz] + bias) * g + b (split-K reduce)
// ---------------------------------------------------------------------------
__global__ __launch_bounds__(256) void reduce_ln_kernel(
    float* __restrict__ out, const float* __restrict__ part,
    const float* __restrict__ bias, const float* __restrict__ resid,
    const float* __restrict__ g, const float* __restrict__ bt)
{
  const int row = blockIdx.x;
  const int t = threadIdx.x;
  const size_t idx = (size_t)row * Dn + t;
  const size_t STR = (size_t)Bb * NQn * Dn;
  float v = part[idx] + part[idx + STR] + part[idx + 2 * STR] + part[idx + 3 * STR]
          + bias[t] + resid[idx];
  float s = v, s2 = v * v;
#pragma unroll
  for (int off = 32; off > 0; off >>= 1) {
    s += __shfl_down(s, off);
    s2 += __shfl_down(s2, off);
  }
  __shared__ float rs[4], rs2[4], fin[2];
  const int lane = t & 63, wid = t >> 6;
  if (lane == 0) { rs[wid] = s; rs2[wid] = s2; }
  __syncthreads();
  if (t == 0) {
    float a = rs[0] + rs[1] + rs[2] + rs[3];
    float a2 = rs2[0] + rs2[1] + rs2[2] + rs2[3];
    float mean = a * (1.f / Dn);
    float var = a2 * (1.f / Dn) - mean * mean;
    fin[0] = mean;
    fin[1] = rsqrtf(var + EPSf);
  }
  __syncthreads();
  out[idx] = (v - fin[0]) * fin[1] * g[t] + bt[t];
}

extern "C" void kernel_launch(void* const* d_in, const int* in_sizes, int n_in,
                              void* d_out, int out_size, void* d_ws, size_t ws_size,
                              hipStream_t stream)
{
  const float* tgt   = (const float*)d_in[0];
  const float* qpos  = (const float*)d_in[1];
  const float* src   = (const float*)d_in[2];
  const float* spe   = (const float*)d_in[3];
  const float* pad   = (const float*)d_in[4];
  const float* rel   = (const float*)d_in[5];
  const float* qw    = (const float*)d_in[6];
  const float* qb    = (const float*)d_in[7];
  const float* kw    = (const float*)d_in[8];
  const float* kb    = (const float*)d_in[9];
  const float* vw    = (const float*)d_in[10];
  const float* vb    = (const float*)d_in[11];
  const float* projw = (const float*)d_in[12];
  const float* projb = (const float*)d_in[13];
  const float* cpbw1 = (const float*)d_in[14];
  const float* cpbb1 = (const float*)d_in[15];
  const float* cpbw2 = (const float*)d_in[16];
  const float* ipw   = (const float*)d_in[17];
  const float* ipb   = (const float*)d_in[18];
  const float* outw  = (const float*)d_in[19];
  const float* outb  = (const float*)d_in[20];
  const float* ln1g  = (const float*)d_in[21];
  const float* ln1b  = (const float*)d_in[22];
  const float* ln2g  = (const float*)d_in[23];
  const float* ln2b  = (const float*)d_in[24];
  const float* ln3g  = (const float*)d_in[25];
  const float* ln3b  = (const float*)d_in[26];
  const float* ff1w  = (const float*)d_in[27];
  const float* ff1b  = (const float*)d_in[28];
  const float* ff2w  = (const float*)d_in[29];
  const float* ff2b  = (const float*)d_in[30];
  float* out = (float*)d_out;
  float* ws = (float*)d_ws;

  constexpr size_t SZ_Q   = (size_t)Bb * NQn * Dn;   // 131072
  constexpr size_t SZ_S   = (size_t)Bb * NSn * Dn;   // 524288
  constexpr size_t SZ_FFH = (size_t)Bb * NQn * FFNn; // 524288

  float* qSb  = ws;
  float* kSb  = qSb + SZ_Q;
  float* vSb  = kSb + SZ_Q;
  float* oSb  = vSb + SZ_Q;
  float* soP  = oSb + SZ_Q;
  float* tgt2 = soP + SZ_Q;
  float* qCb  = tgt2 + SZ_Q;
  float* kCb  = qCb + SZ_Q;
  float* vCb  = kCb + SZ_S;
  float* oCb  = vCb + SZ_S;
  float* coP  = oCb + SZ_Q;
  float* tgt3 = coP + SZ_Q;
  float* ffh  = tgt3 + SZ_Q;
  float* part = ffh + SZ_FFH;           // 4 * SZ_Q
  float* tsb  = part + 4 * SZ_Q;
  float* Stab = tsb + RPEn;
  float* Btab = Stab + (RPEn + 1) * Hn;

  const int MQ = Bb * NQn;  // 512

  // 1. prep: cpb tables + self QKV + cross KV (all independent)
  prep_kernel<<<dim3(96 + 256 + 1), dim3(512), 0, stream>>>(
      qSb, kSb, vSb, kCb, vCb, tgt, qpos, src, spe, ipw, ipb,
      kw, kb, vw, vb, cpbw1, cpbb1, cpbw2, tsb, Stab, Btab);

  // 2. self attention (fused)
  flash_self<<<dim3(NQn / 16, Bb * Hn), dim3(256), 0, stream>>>(
      oSb, qSb, kSb, vSb);

  // 3. self out-proj
  gemm32_kernel<<<dim3(Dn / 32, MQ / 32, 1), dim3(256), 0, stream>>>(
      soP, oSb, nullptr, outw, outb, Dn, Dn, Dn, 1.f);

  // 4. tgt2 = LN2(tgt + soP)
  add_ln_kernel<<<dim3(MQ), dim3(256), 0, stream>>>(tgt2, tgt, soP, ln2g, ln2b);

  // 5. cross q
  gemm32_kernel<<<dim3(Dn / 32, MQ / 32, 1), dim3(256), 0, stream>>>(
      qCb, tgt2, qpos, qw, qb, Dn, Dn, Dn, SCALEf);

  // 6. cross attention (fused, online softmax + RPE bias + pad mask)
  flash_cross<<<dim3(NQn / 16, Bb * Hn), dim3(256), 0, stream>>>(
      oCb, qCb, kCb, vCb, rel, pad, tsb, Stab, Btab);

  // 7. cross out-proj
  gemm32_kernel<<<dim3(Dn / 32, MQ / 32, 1), dim3(256), 0, stream>>>(
      coP, oCb, nullptr, projw, projb, Dn, Dn, Dn, 1.f);

  // 8. tgt3 = LN1(tgt2 + coP)
  add_ln_kernel<<<dim3(MQ), dim3(256), 0, stream>>>(tgt3, tgt2, coP, ln1g, ln1b);

  // 9. FFN1 (relu)
  gemm64_kernel<<<dim3(FFNn / 64, MQ / 64), dim3(512), 0, stream>>>(
      ffh, tgt3, ff1w, ff1b, Dn, FFNn, 1);

  // 10. FFN2 split-K x4 -> partials
  gemm32_kernel<<<dim3(Dn / 32, MQ / 32, 4), dim3(256), 0, stream>>>(
      part, ffh, nullptr, ff2w, nullptr, Dn, 256, FFNn, 1.f);

  // 11. out = LN3(tgt3 + sum(part) + ff2b)
  reduce_ln_kernel<<<dim3(MQ), dim3(256), 0, stream>>>(
      out, part, ff2b, tgt3, ln3g, ln3b);
}

// Round 4
// 185.602 us; speedup vs baseline: 4.1207x; 2.2449x over previous
//
#include <hip/hip_runtime.h>
#include <hip/hip_bf16.h>
#include <math.h>

#define Bb 2
#define NQn 256
#define NSn 1024
#define Dn 256
#define Hn 8
#define DHn 32
#define FFNn 1024
#define RPEn 512
#define SCALEf 0.17677669529663687f
#define EPSf 1e-5f

// ---------------------------------------------------------------------------
// gemm64 body: 64x64 tile, 512 threads. thread -> rows {ty, ty+32}, cols tx*4..+3
// ---------------------------------------------------------------------------
__device__ __forceinline__ void gemm64_body(
    float* __restrict__ C, int ldc,
    const float* __restrict__ A, const float* __restrict__ A2, int ld,
    const float* __restrict__ W, const float* __restrict__ bias,
    int K, int bm, int bnC, int bnW, float scale, int do_relu,
    float (*As)[17], float (*Ws)[17])
{
  const int tid = threadIdx.x;
  const int tx = tid & 15, ty = tid >> 4;  // ty 0..31
  float acc[2][4] = {};
  const int lr = tid >> 3, lc = (tid & 7) * 2;
  for (int k0 = 0; k0 < K; k0 += 16) {
    {
      const float* Ap = A + (size_t)(bm + lr) * ld + k0 + lc;
      float v0 = Ap[0], v1 = Ap[1];
      if (A2) {
        const float* Bp = A2 + (size_t)(bm + lr) * ld + k0 + lc;
        v0 += Bp[0]; v1 += Bp[1];
      }
      As[lr][lc] = v0; As[lr][lc + 1] = v1;
      const float* Wp = W + (size_t)(bnW + lr) * ld + k0 + lc;
      Ws[lr][lc] = Wp[0]; Ws[lr][lc + 1] = Wp[1];
    }
    __syncthreads();
#pragma unroll
    for (int k = 0; k < 16; ++k) {
      float a0 = As[ty][k], a1 = As[ty + 32][k];
      float w0 = Ws[tx * 4 + 0][k], w1 = Ws[tx * 4 + 1][k];
      float w2 = Ws[tx * 4 + 2][k], w3 = Ws[tx * 4 + 3][k];
      acc[0][0] += a0 * w0; acc[0][1] += a0 * w1; acc[0][2] += a0 * w2; acc[0][3] += a0 * w3;
      acc[1][0] += a1 * w0; acc[1][1] += a1 * w1; acc[1][2] += a1 * w2; acc[1][3] += a1 * w3;
    }
    __syncthreads();
  }
#pragma unroll
  for (int i = 0; i < 2; ++i) {
    int m = bm + ty + i * 32;
#pragma unroll
    for (int j = 0; j < 4; ++j) {
      float v = acc[i][j];
      if (bias) v += bias[bnW + tx * 4 + j];
      v *= scale;
      if (do_relu) v = fmaxf(v, 0.f);
      C[(size_t)m * ldc + bnC + tx * 4 + j] = v;
    }
  }
}

// ---------------------------------------------------------------------------
// prep: fused build_cpb (1 block) + self QKV GEMM (96 blocks) + cross KV GEMM
// (256 blocks). 512 threads/block.
// ---------------------------------------------------------------------------
__global__ __launch_bounds__(512) void prep_kernel(
    float* __restrict__ qSb, float* __restrict__ kSb, float* __restrict__ vSb,
    float* __restrict__ kCb, float* __restrict__ vCb,
    const float* __restrict__ tgt, const float* __restrict__ qpos,
    const float* __restrict__ src, const float* __restrict__ spe,
    const float* __restrict__ ipw, const float* __restrict__ ipb,
    const float* __restrict__ kw, const float* __restrict__ kb,
    const float* __restrict__ vw, const float* __restrict__ vb,
    const float* __restrict__ w1p, const float* __restrict__ b1p,
    const float* __restrict__ w2p,
    float* __restrict__ tout, float* __restrict__ Stab, float* __restrict__ Btab)
{
  __shared__ float smem[2176];
  const int bx = blockIdx.x;
  const int tid = threadIdx.x;
  if (bx < 96) {
    float (*As)[17] = (float(*)[17])smem;
    float (*Ws)[17] = (float(*)[17])(smem + 1088);
    int my = bx & 7, nx = bx >> 3;
    int sec = nx >> 2;
    float* C = sec == 0 ? qSb : (sec == 1 ? kSb : vSb);
    gemm64_body(C, Dn, tgt, sec < 2 ? qpos : nullptr, Dn, ipw, ipb,
                Dn, my * 64, (nx & 3) * 64, nx * 64,
                sec == 0 ? SCALEf : 1.f, 0, As, Ws);
    return;
  }
  if (bx < 96 + 256) {
    float (*As)[17] = (float(*)[17])smem;
    float (*Ws)[17] = (float(*)[17])(smem + 1088);
    int idx = bx - 96;
    int my = idx & 31, nx = idx >> 5;
    int sec = nx >> 2;
    gemm64_body(sec ? vCb : kCb, Dn, src, sec ? nullptr : spe, Dn,
                sec ? vw : kw, sec ? vb : kb,
                Dn, my * 64, (nx & 3) * 64, (nx & 3) * 64, 1.f, 0, As, Ws);
    return;
  }
  // ---- cpb piecewise-linear table build (verified rounds 1-3) ----
  float* key = smem;
  int* pidx = (int*)(smem + 512);
  float* w1s = smem + 1024;
  float* b1s = smem + 1536;
  {
    float w = w1p[tid], bb = b1p[tid];
    key[tid] = (w != 0.f) ? (-bb / w) : 3.0e38f;
    pidx[tid] = tid;
  }
  __syncthreads();
  for (int k = 2; k <= RPEn; k <<= 1) {
    for (int j = k >> 1; j > 0; j >>= 1) {
      int ixj = tid ^ j;
      if (ixj > tid) {
        float a = key[tid], c = key[ixj];
        bool asc = ((tid & k) == 0);
        bool sw = asc ? (a > c) : (a < c);
        if (sw) {
          key[tid] = c; key[ixj] = a;
          int tmp = pidx[tid]; pidx[tid] = pidx[ixj]; pidx[ixj] = tmp;
        }
      }
      __syncthreads();
    }
  }
  w1s[tid] = w1p[pidx[tid]];
  b1s[tid] = b1p[pidx[tid]];
  tout[tid] = key[tid];
  __syncthreads();
  const int lane = tid & 63;
  const int h = tid >> 6;
  const int j0 = lane * 8;
  float sp[8], bp[8], sn[8], bn[8];
  float csp = 0.f, cbp = 0.f, csn = 0.f, cbn = 0.f, ccc = 0.f;
#pragma unroll
  for (int e = 0; e < 8; ++e) {
    int j = j0 + e;
    float w = w1s[j], b = b1s[j];
    float c = w2p[h * RPEn + pidx[j]];
    sp[e] = csp; bp[e] = cbp; sn[e] = csn; bn[e] = cbn;
    if (w > 0.f)      { csp += w * c; cbp += b * c; }
    else if (w < 0.f) { csn += w * c; cbn += b * c; }
    else              { ccc += fmaxf(b, 0.f) * c; }
  }
  float isp = csp, ibp = cbp, isn = csn, ibn = cbn, icc = ccc;
#pragma unroll
  for (int d = 1; d < 64; d <<= 1) {
    float t0 = __shfl_up(isp, d);
    float t1 = __shfl_up(ibp, d);
    float t2 = __shfl_up(isn, d);
    float t3 = __shfl_up(ibn, d);
    if (lane >= d) { isp += t0; ibp += t1; isn += t2; ibn += t3; }
    icc += __shfl_xor(icc, d);
  }
  const float tsn = __shfl(isn, 63);
  const float tbn = __shfl(ibn, 63);
  const float esp = isp - csp, ebp = ibp - cbp;
  const float esn = isn - csn, ebn = ibn - cbn;
#pragma unroll
  for (int e = 0; e < 8; ++e) {
    int j = j0 + e;
    Stab[j * Hn + h] = (esp + sp[e]) + (tsn - (esn + sn[e]));
    Btab[j * Hn + h] = (ebp + bp[e]) + (tbn - (ebn + bn[e])) + icc;
  }
  if (lane == 63) {
    Stab[RPEn * Hn + h] = isp;
    Btab[RPEn * Hn + h] = ibp + icc;
  }
}

// ---------------------------------------------------------------------------
// bias_kernel: materialize bias[b,h,q,k] = Sh[lo]*m + Bh[lo] - 100*pad.
// The binary search depends only on (b,q,k) -> done ONCE, applied to 8 heads.
// grid: B*NQ = 512 blocks, 256 threads (4 keys each).
// ---------------------------------------------------------------------------
__global__ __launch_bounds__(256) void bias_kernel(
    float* __restrict__ biasb, const float* __restrict__ rel,
    const float* __restrict__ pad, const float* __restrict__ tsg,
    const float* __restrict__ Stabg, const float* __restrict__ Btabg)
{
  __shared__ float ts[RPEn];
  __shared__ float Sh[(RPEn + 1) * Hn];
  __shared__ float Bh[(RPEn + 1) * Hn];
  const int tid = threadIdx.x;
  const int b = blockIdx.x >> 8, q = blockIdx.x & 255;
  ts[tid] = tsg[tid];
  ts[tid + 256] = tsg[tid + 256];
  for (int i = tid; i < (RPEn + 1) * Hn; i += 256) {
    Sh[i] = Stabg[i];
    Bh[i] = Btabg[i];
  }
  __syncthreads();
#pragma unroll
  for (int j = 0; j < 4; ++j) {
    const int k = tid + j * 256;
    const float m = rel[((size_t)b * NQn + q) * NSn + k];
    const float padv = -100.f * pad[b * NSn + k];
    int lo = 0, hi = RPEn;
#pragma unroll
    for (int it = 0; it < 9; ++it) {
      int mid = (lo + hi) >> 1;
      if (ts[mid] < m) lo = mid + 1; else hi = mid;
    }
#pragma unroll
    for (int h = 0; h < Hn; ++h) {
      biasb[(((size_t)(b * Hn + h)) * NQn + q) * NSn + k] =
          Sh[lo * Hn + h] * m + Bh[lo * Hn + h] + padv;
    }
  }
}

// ---------------------------------------------------------------------------
// Unified flash attention. grid (NQ/8, B*H), 256 threads = (r 0..7, kc 0..31).
// 128-key chunks, online softmax. bias (pre-materialized, incl pad) optional.
// LDS layout Ks[dd*128 + (k^dd)]: staging writes and compute reads both
// conflict-free; lanes 32..63 broadcast-read lanes 0..31's addresses.
// ---------------------------------------------------------------------------
__global__ __launch_bounds__(256) void flash_kernel(
    float* __restrict__ O, const float* __restrict__ Q,
    const float* __restrict__ K, const float* __restrict__ V,
    const float* __restrict__ biasb, int NK)
{
  __shared__ float4 Ks[1024];
  __shared__ float4 Vs[1024];
  __shared__ float4 Qs[64];
  __shared__ float Bs[8 * 128];
  const int bh = blockIdx.y, b = bh >> 3, h = bh & 7;
  const int q0 = blockIdx.x * 8;
  const int tid = threadIdx.x;
  const float4* Kg = (const float4*)K;
  const float4* Vg = (const float4*)V;
  if (tid < 64) {
    int rr = tid >> 3, d4 = tid & 7;
    Qs[tid] = ((const float4*)Q)[(size_t)(b * NQn + q0 + rr) * 64 + h * 8 + d4];
  }
  __syncthreads();
  const int r = tid >> 5, kc = tid & 31;
  float4 q[8];
#pragma unroll
  for (int dd = 0; dd < 8; ++dd) q[dd] = Qs[r * 8 + dd];
  float4 o[8] = {};
  float m_run = -3.0e38f, l_run = 0.f;
  const int nchunk = NK >> 7;
  for (int c = 0; c < nchunk; ++c) {
    const int kb0 = c * 128;
#pragma unroll
    for (int u = 0; u < 4; ++u) {
      int e = tid + u * 256;
      int dd = e & 7, k = e >> 3;
      size_t g = (size_t)(b * NK + kb0 + k) * 64 + h * 8 + dd;
      Ks[dd * 128 + (k ^ dd)] = Kg[g];
      Vs[dd * 128 + (k ^ dd)] = Vg[g];
    }
    if (biasb) {
      const float* bp = biasb + ((size_t)bh * NQn + q0 + (tid >> 5)) * NK + kb0;
      ((float4*)Bs)[tid] = ((const float4*)bp)[tid & 31];
    }
    __syncthreads();
    float s[4];
    float cmax = -3.0e38f;
#pragma unroll
    for (int j = 0; j < 4; ++j) {
      const int k = kc + j * 32;
      float4 a4 = {0.f, 0.f, 0.f, 0.f};
#pragma unroll
      for (int dd = 0; dd < 8; ++dd) {
        float4 kk = Ks[dd * 128 + (k ^ dd)];
        a4.x += q[dd].x * kk.x; a4.y += q[dd].y * kk.y;
        a4.z += q[dd].z * kk.z; a4.w += q[dd].w * kk.w;
      }
      float sv = (a4.x + a4.y) + (a4.z + a4.w);
      if (biasb) sv += Bs[r * 128 + k];
      s[j] = sv;
      cmax = fmaxf(cmax, sv);
    }
#pragma unroll
    for (int off = 1; off < 32; off <<= 1) cmax = fmaxf(cmax, __shfl_xor(cmax, off));
    const float m_new = fmaxf(m_run, cmax);
    const float f = __expf(m_run - m_new);
    float lsum = 0.f;
#pragma unroll
    for (int j = 0; j < 4; ++j) { s[j] = __expf(s[j] - m_new); lsum += s[j]; }
#pragma unroll
    for (int off = 1; off < 32; off <<= 1) lsum += __shfl_xor(lsum, off);
    l_run = l_run * f + lsum;
    m_run = m_new;
#pragma unroll
    for (int dd = 0; dd < 8; ++dd) {
      o[dd].x *= f; o[dd].y *= f; o[dd].z *= f; o[dd].w *= f;
    }
#pragma unroll
    for (int j = 0; j < 4; ++j) {
      const int k = kc + j * 32;
      const float p = s[j];
#pragma unroll
      for (int dd = 0; dd < 8; ++dd) {
        float4 vv = Vs[dd * 128 + (k ^ dd)];
        o[dd].x += p * vv.x; o[dd].y += p * vv.y;
        o[dd].z += p * vv.z; o[dd].w += p * vv.w;
      }
    }
    __syncthreads();
  }
#pragma unroll
  for (int off = 1; off < 32; off <<= 1) {
#pragma unroll
    for (int dd = 0; dd < 8; ++dd) {
      o[dd].x += __shfl_xor(o[dd].x, off);
      o[dd].y += __shfl_xor(o[dd].y, off);
      o[dd].z += __shfl_xor(o[dd].z, off);
      o[dd].w += __shfl_xor(o[dd].w, off);
    }
  }
  if (kc == 0) {
    const float inv = 1.f / l_run;
#pragma unroll
    for (int dd = 0; dd < 8; ++dd) {
      float4 w = o[dd];
      w.x *= inv; w.y *= inv; w.z *= inv; w.w *= inv;
      ((float4*)O)[(size_t)(b * NQn + q0 + r) * 64 + h * 8 + dd] = w;
    }
  }
}

// ---------------------------------------------------------------------------
// gemm64 standalone (FFN1): grid (N/64, M/64), 512 threads.
// ---------------------------------------------------------------------------
__global__ __launch_bounds__(512) void gemm64_kernel(
    float* __restrict__ C, const float* __restrict__ A,
    const float* __restrict__ W, const float* __restrict__ bias,
    int ld, int ldc, int do_relu)
{
  __shared__ float smem[2176];
  float (*As)[17] = (float(*)[17])smem;
  float (*Ws)[17] = (float(*)[17])(smem + 1088);
  gemm64_body(C, ldc, A, nullptr, ld, W, bias, ld,
              blockIdx.y * 64, blockIdx.x * 64, blockIdx.x * 64, 1.f, do_relu,
              As, Ws);
}

// ---------------------------------------------------------------------------
// gemm32: 32x32 tile, 256 threads, 2x2/thread, K-step 32, float4 staging.
// Supports split-K via blockIdx.z (writes partials at kz*M*N).
// ---------------------------------------------------------------------------
__global__ __launch_bounds__(256) void gemm32_kernel(
    float* __restrict__ C, const float* __restrict__ A, const float* __restrict__ A2,
    const float* __restrict__ W, const float* __restrict__ bias,
    int N, int Kchunk, int Ktot, float scale)
{
  __shared__ float As[32][33];
  __shared__ float Ws[32][33];
  const int bm = blockIdx.y * 32, bn = blockIdx.x * 32;
  const int kz = blockIdx.z;
  const int M = gridDim.y * 32;
  float* Cp = C + (size_t)kz * M * N;
  const int tid = threadIdx.x;
  const int tx = tid & 15, ty = tid >> 4;
  const int lr = tid >> 3, lc = (tid & 7) * 4;
  float acc[2][2] = {};
  const int k00 = kz * Kchunk;
  for (int k0 = k00; k0 < k00 + Kchunk; k0 += 32) {
    float4 av = *(const float4*)(A + (size_t)(bm + lr) * Ktot + k0 + lc);
    if (A2) {
      float4 bv = *(const float4*)(A2 + (size_t)(bm + lr) * Ktot + k0 + lc);
      av.x += bv.x; av.y += bv.y; av.z += bv.z; av.w += bv.w;
    }
    As[lr][lc] = av.x; As[lr][lc + 1] = av.y; As[lr][lc + 2] = av.z; As[lr][lc + 3] = av.w;
    float4 wv = *(const float4*)(W + (size_t)(bn + lr) * Ktot + k0 + lc);
    Ws[lr][lc] = wv.x; Ws[lr][lc + 1] = wv.y; Ws[lr][lc + 2] = wv.z; Ws[lr][lc + 3] = wv.w;
    __syncthreads();
#pragma unroll
    for (int k = 0; k < 32; ++k) {
      float a0 = As[ty * 2][k], a1 = As[ty * 2 + 1][k];
      float w0 = Ws[tx * 2][k], w1 = Ws[tx * 2 + 1][k];
      acc[0][0] += a0 * w0; acc[0][1] += a0 * w1;
      acc[1][0] += a1 * w0; acc[1][1] += a1 * w1;
    }
    __syncthreads();
  }
#pragma unroll
  for (int i = 0; i < 2; ++i) {
    int m = bm + ty * 2 + i;
#pragma unroll
    for (int j = 0; j < 2; ++j) {
      int n = bn + tx * 2 + j;
      float v = acc[i][j];
      if (bias) v += bias[n];
      Cp[(size_t)m * N + n] = v * scale;
    }
  }
}

// ---------------------------------------------------------------------------
// out = LayerNorm(x1 + x2) * g + b.  grid: rows, block = 256 = D.
// ---------------------------------------------------------------------------
__global__ __launch_bounds__(256) void add_ln_kernel(
    float* __restrict__ out, const float* __restrict__ x1, const float* __restrict__ x2,
    const float* __restrict__ g, const float* __restrict__ bt)
{
  const int row = blockIdx.x;
  const int t = threadIdx.x;
  const float v = x1[(size_t)row * Dn + t] + x2[(size_t)row * Dn + t];
  float s = v, s2 = v * v;
#pragma unroll
  for (int off = 32; off > 0; off >>= 1) {
    s += __shfl_down(s, off);
    s2 += __shfl_down(s2, off);
  }
  __shared__ float rs[4], rs2[4], fin[2];
  const int lane = t & 63, wid = t >> 6;
  if (lane == 0) { rs[wid] = s; rs2[wid] = s2; }
  __syncthreads();
  if (t == 0) {
    float a = rs[0] + rs[1] + rs[2] + rs[3];
    float a2 = rs2[0] + rs2[1] + rs2[2] + rs2[3];
    float mean = a * (1.f / Dn);
    float var = a2 * (1.f / Dn) - mean * mean;
    fin[0] = mean;
    fin[1] = rsqrtf(var + EPSf);
  }
  __syncthreads();
  out[(size_t)row * Dn + t] = (v - fin[0]) * fin[1] * g[t] + bt[t];
}

// ---------------------------------------------------------------------------
// out = LayerNorm(resid + sum_{kz<4} part[kz] + bias) * g + b (split-K reduce)
// ---------------------------------------------------------------------------
__global__ __launch_bounds__(256) void reduce_ln_kernel(
    float* __restrict__ out, const float* __restrict__ part,
    const float* __restrict__ bias, const float* __restrict__ resid,
    const float* __restrict__ g, const float* __restrict__ bt)
{
  const int row = blockIdx.x;
  const int t = threadIdx.x;
  const size_t idx = (size_t)row * Dn + t;
  const size_t STR = (size_t)Bb * NQn * Dn;
  float v = part[idx] + part[idx + STR] + part[idx + 2 * STR] + part[idx + 3 * STR]
          + bias[t] + resid[idx];
  float s = v, s2 = v * v;
#pragma unroll
  for (int off = 32; off > 0; off >>= 1) {
    s += __shfl_down(s, off);
    s2 += __shfl_down(s2, off);
  }
  __shared__ float rs[4], rs2[4], fin[2];
  const int lane = t & 63, wid = t >> 6;
  if (lane == 0) { rs[wid] = s; rs2[wid] = s2; }
  __syncthreads();
  if (t == 0) {
    float a = rs[0] + rs[1] + rs[2] + rs[3];
    float a2 = rs2[0] + rs2[1] + rs2[2] + rs2[3];
    float mean = a * (1.f / Dn);
    float var = a2 * (1.f / Dn) - mean * mean;
    fin[0] = mean;
    fin[1] = rsqrtf(var + EPSf);
  }
  __syncthreads();
  out[idx] = (v - fin[0]) * fin[1] * g[t] + bt[t];
}

extern "C" void kernel_launch(void* const* d_in, const int* in_sizes, int n_in,
                              void* d_out, int out_size, void* d_ws, size_t ws_size,
                              hipStream_t stream)
{
  const float* tgt   = (const float*)d_in[0];
  const float* qpos  = (const float*)d_in[1];
  const float* src   = (const float*)d_in[2];
  const float* spe   = (const float*)d_in[3];
  const float* pad   = (const float*)d_in[4];
  const float* rel   = (const float*)d_in[5];
  const float* qw    = (const float*)d_in[6];
  const float* qb    = (const float*)d_in[7];
  const float* kw    = (const float*)d_in[8];
  const float* kb    = (const float*)d_in[9];
  const float* vw    = (const float*)d_in[10];
  const float* vb    = (const float*)d_in[11];
  const float* projw = (const float*)d_in[12];
  const float* projb = (const float*)d_in[13];
  const float* cpbw1 = (const float*)d_in[14];
  const float* cpbb1 = (const float*)d_in[15];
  const float* cpbw2 = (const float*)d_in[16];
  const float* ipw   = (const float*)d_in[17];
  const float* ipb   = (const float*)d_in[18];
  const float* outw  = (const float*)d_in[19];
  const float* outb  = (const float*)d_in[20];
  const float* ln1g  = (const float*)d_in[21];
  const float* ln1b  = (const float*)d_in[22];
  const float* ln2g  = (const float*)d_in[23];
  const float* ln2b  = (const float*)d_in[24];
  const float* ln3g  = (const float*)d_in[25];
  const float* ln3b  = (const float*)d_in[26];
  const float* ff1w  = (const float*)d_in[27];
  const float* ff1b  = (const float*)d_in[28];
  const float* ff2w  = (const float*)d_in[29];
  const float* ff2b  = (const float*)d_in[30];
  float* out = (float*)d_out;
  float* ws = (float*)d_ws;

  constexpr size_t SZ_Q   = (size_t)Bb * NQn * Dn;   // 131072
  constexpr size_t SZ_S   = (size_t)Bb * NSn * Dn;   // 524288
  constexpr size_t SZ_FFH = (size_t)Bb * NQn * FFNn; // 524288
  constexpr size_t SZ_BIAS = (size_t)Bb * Hn * NQn * NSn; // 4194304

  float* qSb  = ws;
  float* kSb  = qSb + SZ_Q;
  float* vSb  = kSb + SZ_Q;
  float* oSb  = vSb + SZ_Q;
  float* soP  = oSb + SZ_Q;
  float* tgt2 = soP + SZ_Q;
  float* qCb  = tgt2 + SZ_Q;
  float* kCb  = qCb + SZ_Q;
  float* vCb  = kCb + SZ_S;
  float* oCb  = vCb + SZ_S;
  float* coP  = oCb + SZ_Q;
  float* tgt3 = coP + SZ_Q;
  float* ffh  = tgt3 + SZ_Q;
  float* part = ffh + SZ_FFH;           // 4 * SZ_Q
  float* tsb  = part + 4 * SZ_Q;
  float* Stab = tsb + RPEn;
  float* Btab = Stab + (RPEn + 1) * Hn;
  float* biasb = Btab + (RPEn + 1) * Hn;

  const int MQ = Bb * NQn;  // 512

  // 1. prep: cpb tables + self QKV + cross KV (all independent)
  prep_kernel<<<dim3(96 + 256 + 1), dim3(512), 0, stream>>>(
      qSb, kSb, vSb, kCb, vCb, tgt, qpos, src, spe, ipw, ipb,
      kw, kb, vw, vb, cpbw1, cpbb1, cpbw2, tsb, Stab, Btab);

  // 2. materialize cross-attn bias (search once per (b,q,k), 8 heads)
  bias_kernel<<<dim3(Bb * NQn), dim3(256), 0, stream>>>(
      biasb, rel, pad, tsb, Stab, Btab);

  // 3. self attention (fused flash)
  flash_kernel<<<dim3(NQn / 8, Bb * Hn), dim3(256), 0, stream>>>(
      oSb, qSb, kSb, vSb, nullptr, NQn);

  // 4. self out-proj
  gemm32_kernel<<<dim3(Dn / 32, MQ / 32, 1), dim3(256), 0, stream>>>(
      soP, oSb, nullptr, outw, outb, Dn, Dn, Dn, 1.f);

  // 5. tgt2 = LN2(tgt + soP)
  add_ln_kernel<<<dim3(MQ), dim3(256), 0, stream>>>(tgt2, tgt, soP, ln2g, ln2b);

  // 6. cross q
  gemm32_kernel<<<dim3(Dn / 32, MQ / 32, 1), dim3(256), 0, stream>>>(
      qCb, tgt2, qpos, qw, qb, Dn, Dn, Dn, SCALEf);

  // 7. cross attention (fused flash + staged bias)
  flash_kernel<<<dim3(NQn / 8, Bb * Hn), dim3(256), 0, stream>>>(
      oCb, qCb, kCb, vCb, biasb, NSn);

  // 8. cross out-proj
  gemm32_kernel<<<dim3(Dn / 32, MQ / 32, 1), dim3(256), 0, stream>>>(
      coP, oCb, nullptr, projw, projb, Dn, Dn, Dn, 1.f);

  // 9. tgt3 = LN1(tgt2 + coP)
  add_ln_kernel<<<dim3(MQ), dim3(256), 0, stream>>>(tgt3, tgt2, coP, ln1g, ln1b);

  // 10. FFN1 (relu)
  gemm64_kernel<<<dim3(FFNn / 64, MQ / 64), dim3(512), 0, stream>>>(
      ffh, tgt3, ff1w, ff1b, Dn, FFNn, 1);

  // 11. FFN2 split-K x4 -> partials
  gemm32_kernel<<<dim3(Dn / 32, MQ / 32, 4), dim3(256), 0, stream>>>(
      part, ffh, nullptr, ff2w, nullptr, Dn, 256, FFNn, 1.f);

  // 12. out = LN3(tgt3 + sum(part) + ff2b)
  reduce_ln_kernel<<<dim3(MQ), dim3(256), 0, stream>>>(
      out, part, ff2b, tgt3, ln3g, ln3b);
}

// Round 5
// 165.725 us; speedup vs baseline: 4.6149x; 1.1199x over previous
//
#include <hip/hip_runtime.h>
#include <hip/hip_bf16.h>
#include <math.h>

#define Bb 2
#define NQn 256
#define NSn 1024
#define Dn 256
#define Hn 8
#define DHn 32
#define FFNn 1024
#define RPEn 512
#define SCALEf 0.17677669529663687f
#define EPSf 1e-5f

// ---------------------------------------------------------------------------
// gemm64 body v2: 64x64 tile, 512 threads, K-step 32, float4 global loads,
// register prefetch (next K-chunk loaded during compute of current).
// LDS: As[64][33] row-major (reads are 4-addr broadcast, conflict-free);
//      WsT[32][68] k-major so inner loop reads W as aligned ds_read_b128.
// thread -> rows {ty, ty+32}, cols tx*4..+3.
// ---------------------------------------------------------------------------
__device__ __forceinline__ void gemm64_body(
    float* __restrict__ C, int ldc,
    const float* __restrict__ A, const float* __restrict__ A2, int ld,
    const float* __restrict__ W, const float* __restrict__ bias,
    int K, int bm, int bnC, int bnW, float scale, int do_relu,
    float (*As)[33], float (*WsT)[68])
{
  const int tid = threadIdx.x;
  const int tx = tid & 15, ty = tid >> 4;       // ty 0..31
  const int lr = tid >> 3, lc = (tid & 7) * 4;  // staging coords
  float4 ra, rw;
  {
    ra = *(const float4*)(A + (size_t)(bm + lr) * ld + lc);
    if (A2) {
      float4 t = *(const float4*)(A2 + (size_t)(bm + lr) * ld + lc);
      ra.x += t.x; ra.y += t.y; ra.z += t.z; ra.w += t.w;
    }
    rw = *(const float4*)(W + (size_t)(bnW + lr) * ld + lc);
  }
  float acc[2][4] = {};
  for (int k0 = 0; k0 < K; k0 += 32) {
    As[lr][lc] = ra.x; As[lr][lc + 1] = ra.y;
    As[lr][lc + 2] = ra.z; As[lr][lc + 3] = ra.w;
    WsT[lc][lr] = rw.x; WsT[lc + 1][lr] = rw.y;
    WsT[lc + 2][lr] = rw.z; WsT[lc + 3][lr] = rw.w;
    __syncthreads();
    if (k0 + 32 < K) {
      ra = *(const float4*)(A + (size_t)(bm + lr) * ld + k0 + 32 + lc);
      if (A2) {
        float4 t = *(const float4*)(A2 + (size_t)(bm + lr) * ld + k0 + 32 + lc);
        ra.x += t.x; ra.y += t.y; ra.z += t.z; ra.w += t.w;
      }
      rw = *(const float4*)(W + (size_t)(bnW + lr) * ld + k0 + 32 + lc);
    }
#pragma unroll
    for (int k = 0; k < 32; ++k) {
      float a0 = As[ty][k], a1 = As[ty + 32][k];
      float4 w = *(const float4*)&WsT[k][tx * 4];
      acc[0][0] += a0 * w.x; acc[0][1] += a0 * w.y;
      acc[0][2] += a0 * w.z; acc[0][3] += a0 * w.w;
      acc[1][0] += a1 * w.x; acc[1][1] += a1 * w.y;
      acc[1][2] += a1 * w.z; acc[1][3] += a1 * w.w;
    }
    __syncthreads();
  }
#pragma unroll
  for (int i = 0; i < 2; ++i) {
    int m = bm + ty + i * 32;
#pragma unroll
    for (int j = 0; j < 4; ++j) {
      float v = acc[i][j];
      if (bias) v += bias[bnW + tx * 4 + j];
      v *= scale;
      if (do_relu) v = fmaxf(v, 0.f);
      C[(size_t)m * ldc + bnC + tx * 4 + j] = v;
    }
  }
}

// ---------------------------------------------------------------------------
// prep: fused build_cpb (1 block) + self QKV GEMM (96 blocks) + cross KV GEMM
// (256 blocks). 512 threads/block.
// ---------------------------------------------------------------------------
__global__ __launch_bounds__(512) void prep_kernel(
    float* __restrict__ qSb, float* __restrict__ kSb, float* __restrict__ vSb,
    float* __restrict__ kCb, float* __restrict__ vCb,
    const float* __restrict__ tgt, const float* __restrict__ qpos,
    const float* __restrict__ src, const float* __restrict__ spe,
    const float* __restrict__ ipw, const float* __restrict__ ipb,
    const float* __restrict__ kw, const float* __restrict__ kb,
    const float* __restrict__ vw, const float* __restrict__ vb,
    const float* __restrict__ w1p, const float* __restrict__ b1p,
    const float* __restrict__ w2p,
    float* __restrict__ tout, float* __restrict__ Stab, float* __restrict__ Btab)
{
  __shared__ float smem[4288];  // As 64*33=2112 + WsT 32*68=2176
  const int bx = blockIdx.x;
  const int tid = threadIdx.x;
  if (bx < 96) {
    float (*As)[33] = (float(*)[33])smem;
    float (*WsT)[68] = (float(*)[68])(smem + 2112);
    int my = bx & 7, nx = bx >> 3;
    int sec = nx >> 2;
    float* C = sec == 0 ? qSb : (sec == 1 ? kSb : vSb);
    gemm64_body(C, Dn, tgt, sec < 2 ? qpos : nullptr, Dn, ipw, ipb,
                Dn, my * 64, (nx & 3) * 64, nx * 64,
                sec == 0 ? SCALEf : 1.f, 0, As, WsT);
    return;
  }
  if (bx < 96 + 256) {
    float (*As)[33] = (float(*)[33])smem;
    float (*WsT)[68] = (float(*)[68])(smem + 2112);
    int idx = bx - 96;
    int my = idx & 31, nx = idx >> 5;
    int sec = nx >> 2;
    gemm64_body(sec ? vCb : kCb, Dn, src, sec ? nullptr : spe, Dn,
                sec ? vw : kw, sec ? vb : kb,
                Dn, my * 64, (nx & 3) * 64, (nx & 3) * 64, 1.f, 0, As, WsT);
    return;
  }
  // ---- cpb piecewise-linear table build (verified rounds 1-4) ----
  float* key = smem;
  int* pidx = (int*)(smem + 512);
  float* w1s = smem + 1024;
  float* b1s = smem + 1536;
  {
    float w = w1p[tid], bb = b1p[tid];
    key[tid] = (w != 0.f) ? (-bb / w) : 3.0e38f;
    pidx[tid] = tid;
  }
  __syncthreads();
  for (int k = 2; k <= RPEn; k <<= 1) {
    for (int j = k >> 1; j > 0; j >>= 1) {
      int ixj = tid ^ j;
      if (ixj > tid) {
        float a = key[tid], c = key[ixj];
        bool asc = ((tid & k) == 0);
        bool sw = asc ? (a > c) : (a < c);
        if (sw) {
          key[tid] = c; key[ixj] = a;
          int tmp = pidx[tid]; pidx[tid] = pidx[ixj]; pidx[ixj] = tmp;
        }
      }
      __syncthreads();
    }
  }
  w1s[tid] = w1p[pidx[tid]];
  b1s[tid] = b1p[pidx[tid]];
  tout[tid] = key[tid];
  __syncthreads();
  const int lane = tid & 63;
  const int h = tid >> 6;
  const int j0 = lane * 8;
  float sp[8], bp[8], sn[8], bn[8];
  float csp = 0.f, cbp = 0.f, csn = 0.f, cbn = 0.f, ccc = 0.f;
#pragma unroll
  for (int e = 0; e < 8; ++e) {
    int j = j0 + e;
    float w = w1s[j], b = b1s[j];
    float c = w2p[h * RPEn + pidx[j]];
    sp[e] = csp; bp[e] = cbp; sn[e] = csn; bn[e] = cbn;
    if (w > 0.f)      { csp += w * c; cbp += b * c; }
    else if (w < 0.f) { csn += w * c; cbn += b * c; }
    else              { ccc += fmaxf(b, 0.f) * c; }
  }
  float isp = csp, ibp = cbp, isn = csn, ibn = cbn, icc = ccc;
#pragma unroll
  for (int d = 1; d < 64; d <<= 1) {
    float t0 = __shfl_up(isp, d);
    float t1 = __shfl_up(ibp, d);
    float t2 = __shfl_up(isn, d);
    float t3 = __shfl_up(ibn, d);
    if (lane >= d) { isp += t0; ibp += t1; isn += t2; ibn += t3; }
    icc += __shfl_xor(icc, d);
  }
  const float tsn = __shfl(isn, 63);
  const float tbn = __shfl(ibn, 63);
  const float esp = isp - csp, ebp = ibp - cbp;
  const float esn = isn - csn, ebn = ibn - cbn;
#pragma unroll
  for (int e = 0; e < 8; ++e) {
    int j = j0 + e;
    Stab[j * Hn + h] = (esp + sp[e]) + (tsn - (esn + sn[e]));
    Btab[j * Hn + h] = (ebp + bp[e]) + (tbn - (ebn + bn[e])) + icc;
  }
  if (lane == 63) {
    Stab[RPEn * Hn + h] = isp;
    Btab[RPEn * Hn + h] = ibp + icc;
  }
}

// ---------------------------------------------------------------------------
// bias_kernel: materialize bias[b,h,q,k] = Sh[lo]*m + Bh[lo] - 100*pad.
// Binary search depends only on (b,q,k) -> done ONCE, applied to 8 heads.
// ---------------------------------------------------------------------------
__global__ __launch_bounds__(256) void bias_kernel(
    float* __restrict__ biasb, const float* __restrict__ rel,
    const float* __restrict__ pad, const float* __restrict__ tsg,
    const float* __restrict__ Stabg, const float* __restrict__ Btabg)
{
  __shared__ float ts[RPEn];
  __shared__ float Sh[(RPEn + 1) * Hn];
  __shared__ float Bh[(RPEn + 1) * Hn];
  const int tid = threadIdx.x;
  const int b = blockIdx.x >> 8, q = blockIdx.x & 255;
  ts[tid] = tsg[tid];
  ts[tid + 256] = tsg[tid + 256];
  for (int i = tid; i < (RPEn + 1) * Hn; i += 256) {
    Sh[i] = Stabg[i];
    Bh[i] = Btabg[i];
  }
  __syncthreads();
#pragma unroll
  for (int j = 0; j < 4; ++j) {
    const int k = tid + j * 256;
    const float m = rel[((size_t)b * NQn + q) * NSn + k];
    const float padv = -100.f * pad[b * NSn + k];
    int lo = 0, hi = RPEn;
#pragma unroll
    for (int it = 0; it < 9; ++it) {
      int mid = (lo + hi) >> 1;
      if (ts[mid] < m) lo = mid + 1; else hi = mid;
    }
#pragma unroll
    for (int h = 0; h < Hn; ++h) {
      biasb[(((size_t)(b * Hn + h)) * NQn + q) * NSn + k] =
          Sh[lo * Hn + h] * m + Bh[lo * Hn + h] + padv;
    }
  }
}

// ---------------------------------------------------------------------------
// Unified flash attention with optional key-split (flash-decoding).
// grid (NQ/8, B*H, nsplit), 256 threads = (r 0..7, kc 0..31).
// Each split handles NK/nsplit keys in 128-key chunks with online softmax.
// nsplit==1: writes normalized O. nsplit>1: writes unnormalized partials
// po[sp][bh][q][32] + pm/pl[sp][bh][q] for flash_combine.
// ---------------------------------------------------------------------------
__global__ __launch_bounds__(256) void flash_kernel(
    float* __restrict__ O, const float* __restrict__ Q,
    const float* __restrict__ K, const float* __restrict__ V,
    const float* __restrict__ biasb, int NK,
    float* __restrict__ po, float* __restrict__ pm, float* __restrict__ pl)
{
  __shared__ float4 Ks[1024];
  __shared__ float4 Vs[1024];
  __shared__ float4 Qs[64];
  __shared__ float Bs[8 * 128];
  const int bh = blockIdx.y, b = bh >> 3, h = bh & 7;
  const int q0 = blockIdx.x * 8;
  const int sp = blockIdx.z, nsp = gridDim.z;
  const int nkloc = NK / nsp;
  const int kstart = sp * nkloc;
  const int tid = threadIdx.x;
  const float4* Kg = (const float4*)K;
  const float4* Vg = (const float4*)V;
  if (tid < 64) {
    int rr = tid >> 3, d4 = tid & 7;
    Qs[tid] = ((const float4*)Q)[(size_t)(b * NQn + q0 + rr) * 64 + h * 8 + d4];
  }
  __syncthreads();
  const int r = tid >> 5, kc = tid & 31;
  float4 q[8];
#pragma unroll
  for (int dd = 0; dd < 8; ++dd) q[dd] = Qs[r * 8 + dd];
  float4 o[8] = {};
  float m_run = -3.0e38f, l_run = 0.f;
  const int nchunk = nkloc >> 7;
  for (int c = 0; c < nchunk; ++c) {
    const int kb0 = kstart + c * 128;
#pragma unroll
    for (int u = 0; u < 4; ++u) {
      int e = tid + u * 256;
      int dd = e & 7, k = e >> 3;
      size_t g = (size_t)(b * NK + kb0 + k) * 64 + h * 8 + dd;
      Ks[dd * 128 + (k ^ dd)] = Kg[g];
      Vs[dd * 128 + (k ^ dd)] = Vg[g];
    }
    if (biasb) {
      const float* bp = biasb + ((size_t)bh * NQn + q0 + r) * NK + kb0;
      ((float4*)Bs)[tid] = ((const float4*)bp)[kc];
    }
    __syncthreads();
    float s[4];
    float cmax = -3.0e38f;
#pragma unroll
    for (int j = 0; j < 4; ++j) {
      const int k = kc + j * 32;
      float4 a4 = {0.f, 0.f, 0.f, 0.f};
#pragma unroll
      for (int dd = 0; dd < 8; ++dd) {
        float4 kk = Ks[dd * 128 + (k ^ dd)];
        a4.x += q[dd].x * kk.x; a4.y += q[dd].y * kk.y;
        a4.z += q[dd].z * kk.z; a4.w += q[dd].w * kk.w;
      }
      float sv = (a4.x + a4.y) + (a4.z + a4.w);
      if (biasb) sv += Bs[r * 128 + k];
      s[j] = sv;
      cmax = fmaxf(cmax, sv);
    }
#pragma unroll
    for (int off = 1; off < 32; off <<= 1) cmax = fmaxf(cmax, __shfl_xor(cmax, off));
    const float m_new = fmaxf(m_run, cmax);
    const float f = __expf(m_run - m_new);
    float lsum = 0.f;
#pragma unroll
    for (int j = 0; j < 4; ++j) { s[j] = __expf(s[j] - m_new); lsum += s[j]; }
#pragma unroll
    for (int off = 1; off < 32; off <<= 1) lsum += __shfl_xor(lsum, off);
    l_run = l_run * f + lsum;
    m_run = m_new;
#pragma unroll
    for (int dd = 0; dd < 8; ++dd) {
      o[dd].x *= f; o[dd].y *= f; o[dd].z *= f; o[dd].w *= f;
    }
#pragma unroll
    for (int j = 0; j < 4; ++j) {
      const int k = kc + j * 32;
      const float p = s[j];
#pragma unroll
      for (int dd = 0; dd < 8; ++dd) {
        float4 vv = Vs[dd * 128 + (k ^ dd)];
        o[dd].x += p * vv.x; o[dd].y += p * vv.y;
        o[dd].z += p * vv.z; o[dd].w += p * vv.w;
      }
    }
    __syncthreads();
  }
#pragma unroll
  for (int off = 1; off < 32; off <<= 1) {
#pragma unroll
    for (int dd = 0; dd < 8; ++dd) {
      o[dd].x += __shfl_xor(o[dd].x, off);
      o[dd].y += __shfl_xor(o[dd].y, off);
      o[dd].z += __shfl_xor(o[dd].z, off);
      o[dd].w += __shfl_xor(o[dd].w, off);
    }
  }
  if (kc == 0) {
    if (nsp == 1) {
      const float inv = 1.f / l_run;
#pragma unroll
      for (int dd = 0; dd < 8; ++dd) {
        float4 w = o[dd];
        w.x *= inv; w.y *= inv; w.z *= inv; w.w *= inv;
        ((float4*)O)[(size_t)(b * NQn + q0 + r) * 64 + h * 8 + dd] = w;
      }
    } else {
      const int prow = (sp * Bb * Hn + bh) * NQn + q0 + r;
#pragma unroll
      for (int dd = 0; dd < 8; ++dd)
        ((float4*)po)[(size_t)prow * 8 + dd] = o[dd];
      pm[prow] = m_run;
      pl[prow] = l_run;
    }
  }
}

// ---------------------------------------------------------------------------
// flash_combine: merge nsp split partials. grid B*H*NQ/8 blocks, 256 threads
// (8 rows x 32 dh per block).
// ---------------------------------------------------------------------------
__global__ __launch_bounds__(256) void flash_combine(
    float* __restrict__ O, const float* __restrict__ po,
    const float* __restrict__ pm, const float* __restrict__ pl, int nsp)
{
  const int t = threadIdx.x;
  const int row = blockIdx.x * 8 + (t >> 5);  // bh*NQ + q
  const int dh = t & 31;
  const int bh = row >> 8, q = row & 255;
  const int b = bh >> 3, h = bh & 7;
  const int NR = Bb * Hn * NQn;  // 4096
  float m = -3.0e38f;
  for (int s = 0; s < nsp; ++s) m = fmaxf(m, pm[s * NR + row]);
  float osum = 0.f, lsum = 0.f;
  for (int s = 0; s < nsp; ++s) {
    const float w = __expf(pm[s * NR + row] - m);
    osum += w * po[(size_t)(s * NR + row) * 32 + dh];
    lsum += w * pl[s * NR + row];
  }
  O[((size_t)(b * NQn + q)) * Dn + h * DHn + dh] = osum / lsum;
}

// ---------------------------------------------------------------------------
// gemm64 standalone (FFN1): grid (N/64, M/64), 512 threads.
// ---------------------------------------------------------------------------
__global__ __launch_bounds__(512) void gemm64_kernel(
    float* __restrict__ C, const float* __restrict__ A,
    const float* __restrict__ W, const float* __restrict__ bias,
    int ld, int ldc, int do_relu)
{
  __shared__ float smem[4288];
  float (*As)[33] = (float(*)[33])smem;
  float (*WsT)[68] = (float(*)[68])(smem + 2112);
  gemm64_body(C, ldc, A, nullptr, ld, W, bias, ld,
              blockIdx.y * 64, blockIdx.x * 64, blockIdx.x * 64, 1.f, do_relu,
              As, WsT);
}

// ---------------------------------------------------------------------------
// gemm32: 32x32 tile, 256 threads, 2x2/thread, K-step 32, float4 staging with
// register prefetch. Split-K via blockIdx.z (partials at kz*M*N).
// ---------------------------------------------------------------------------
__global__ __launch_bounds__(256) void gemm32_kernel(
    float* __restrict__ C, const float* __restrict__ A, const float* __restrict__ A2,
    const float* __restrict__ W, const float* __restrict__ bias,
    int N, int Kchunk, int Ktot, float scale)
{
  __shared__ float As[32][33];
  __shared__ float Ws[32][33];
  const int bm = blockIdx.y * 32, bn = blockIdx.x * 32;
  const int kz = blockIdx.z;
  const int M = gridDim.y * 32;
  float* Cp = C + (size_t)kz * M * N;
  const int tid = threadIdx.x;
  const int tx = tid & 15, ty = tid >> 4;
  const int lr = tid >> 3, lc = (tid & 7) * 4;
  float acc[2][2] = {};
  const int k00 = kz * Kchunk;
  float4 av, wv;
  {
    av = *(const float4*)(A + (size_t)(bm + lr) * Ktot + k00 + lc);
    if (A2) {
      float4 bv = *(const float4*)(A2 + (size_t)(bm + lr) * Ktot + k00 + lc);
      av.x += bv.x; av.y += bv.y; av.z += bv.z; av.w += bv.w;
    }
    wv = *(const float4*)(W + (size_t)(bn + lr) * Ktot + k00 + lc);
  }
  for (int k0 = k00; k0 < k00 + Kchunk; k0 += 32) {
    As[lr][lc] = av.x; As[lr][lc + 1] = av.y; As[lr][lc + 2] = av.z; As[lr][lc + 3] = av.w;
    Ws[lr][lc] = wv.x; Ws[lr][lc + 1] = wv.y; Ws[lr][lc + 2] = wv.z; Ws[lr][lc + 3] = wv.w;
    __syncthreads();
    if (k0 + 32 < k00 + Kchunk) {
      av = *(const float4*)(A + (size_t)(bm + lr) * Ktot + k0 + 32 + lc);
      if (A2) {
        float4 bv = *(const float4*)(A2 + (size_t)(bm + lr) * Ktot + k0 + 32 + lc);
        av.x += bv.x; av.y += bv.y; av.z += bv.z; av.w += bv.w;
      }
      wv = *(const float4*)(W + (size_t)(bn + lr) * Ktot + k0 + 32 + lc);
    }
#pragma unroll
    for (int k = 0; k < 32; ++k) {
      float a0 = As[ty * 2][k], a1 = As[ty * 2 + 1][k];
      float w0 = Ws[tx * 2][k], w1 = Ws[tx * 2 + 1][k];
      acc[0][0] += a0 * w0; acc[0][1] += a0 * w1;
      acc[1][0] += a1 * w0; acc[1][1] += a1 * w1;
    }
    __syncthreads();
  }
#pragma unroll
  for (int i = 0; i < 2; ++i) {
    int m = bm + ty * 2 + i;
#pragma unroll
    for (int j = 0; j < 2; ++j) {
      int n = bn + tx * 2 + j;
      float v = acc[i][j];
      if (bias) v += bias[n];
      Cp[(size_t)m * N + n] = v * scale;
    }
  }
}

// ---------------------------------------------------------------------------
// out = LayerNorm(x1 + x2) * g + b.  grid: rows, block = 256 = D.
// ---------------------------------------------------------------------------
__global__ __launch_bounds__(256) void add_ln_kernel(
    float* __restrict__ out, const float* __restrict__ x1, const float* __restrict__ x2,
    const float* __restrict__ g, const float* __restrict__ bt)
{
  const int row = blockIdx.x;
  const int t = threadIdx.x;
  const float v = x1[(size_t)row * Dn + t] + x2[(size_t)row * Dn + t];
  float s = v, s2 = v * v;
#pragma unroll
  for (int off = 32; off > 0; off >>= 1) {
    s += __shfl_down(s, off);
    s2 += __shfl_down(s2, off);
  }
  __shared__ float rs[4], rs2[4], fin[2];
  const int lane = t & 63, wid = t >> 6;
  if (lane == 0) { rs[wid] = s; rs2[wid] = s2; }
  __syncthreads();
  if (t == 0) {
    float a = rs[0] + rs[1] + rs[2] + rs[3];
    float a2 = rs2[0] + rs2[1] + rs2[2] + rs2[3];
    float mean = a * (1.f / Dn);
    float var = a2 * (1.f / Dn) - mean * mean;
    fin[0] = mean;
    fin[1] = rsqrtf(var + EPSf);
  }
  __syncthreads();
  out[(size_t)row * Dn + t] = (v - fin[0]) * fin[1] * g[t] + bt[t];
}

// ---------------------------------------------------------------------------
// out = LayerNorm(resid + sum_{kz<4} part[kz] + bias) * g + b (split-K reduce)
// ---------------------------------------------------------------------------
__global__ __launch_bounds__(256) void reduce_ln_kernel(
    float* __restrict__ out, const float* __restrict__ part,
    const float* __restrict__ bias, const float* __restrict__ resid,
    const float* __restrict__ g, const float* __restrict__ bt)
{
  const int row = blockIdx.x;
  const int t = threadIdx.x;
  const size_t idx = (size_t)row * Dn + t;
  const size_t STR = (size_t)Bb * NQn * Dn;
  float v = part[idx] + part[idx + STR] + part[idx + 2 * STR] + part[idx + 3 * STR]
          + bias[t] + resid[idx];
  float s = v, s2 = v * v;
#pragma unroll
  for (int off = 32; off > 0; off >>= 1) {
    s += __shfl_down(s, off);
    s2 += __shfl_down(s2, off);
  }
  __shared__ float rs[4], rs2[4], fin[2];
  const int lane = t & 63, wid = t >> 6;
  if (lane == 0) { rs[wid] = s; rs2[wid] = s2; }
  __syncthreads();
  if (t == 0) {
    float a = rs[0] + rs[1] + rs[2] + rs[3];
    float a2 = rs2[0] + rs2[1] + rs2[2] + rs2[3];
    float mean = a * (1.f / Dn);
    float var = a2 * (1.f / Dn) - mean * mean;
    fin[0] = mean;
    fin[1] = rsqrtf(var + EPSf);
  }
  __syncthreads();
  out[idx] = (v - fin[0]) * fin[1] * g[t] + bt[t];
}

extern "C" void kernel_launch(void* const* d_in, const int* in_sizes, int n_in,
                              void* d_out, int out_size, void* d_ws, size_t ws_size,
                              hipStream_t stream)
{
  const float* tgt   = (const float*)d_in[0];
  const float* qpos  = (const float*)d_in[1];
  const float* src   = (const float*)d_in[2];
  const float* spe   = (const float*)d_in[3];
  const float* pad   = (const float*)d_in[4];
  const float* rel   = (const float*)d_in[5];
  const float* qw    = (const float*)d_in[6];
  const float* qb    = (const float*)d_in[7];
  const float* kw    = (const float*)d_in[8];
  const float* kb    = (const float*)d_in[9];
  const float* vw    = (const float*)d_in[10];
  const float* vb    = (const float*)d_in[11];
  const float* projw = (const float*)d_in[12];
  const float* projb = (const float*)d_in[13];
  const float* cpbw1 = (const float*)d_in[14];
  const float* cpbb1 = (const float*)d_in[15];
  const float* cpbw2 = (const float*)d_in[16];
  const float* ipw   = (const float*)d_in[17];
  const float* ipb   = (const float*)d_in[18];
  const float* outw  = (const float*)d_in[19];
  const float* outb  = (const float*)d_in[20];
  const float* ln1g  = (const float*)d_in[21];
  const float* ln1b  = (const float*)d_in[22];
  const float* ln2g  = (const float*)d_in[23];
  const float* ln2b  = (const float*)d_in[24];
  const float* ln3g  = (const float*)d_in[25];
  const float* ln3b  = (const float*)d_in[26];
  const float* ff1w  = (const float*)d_in[27];
  const float* ff1b  = (const float*)d_in[28];
  const float* ff2w  = (const float*)d_in[29];
  const float* ff2b  = (const float*)d_in[30];
  float* out = (float*)d_out;
  float* ws = (float*)d_ws;

  constexpr size_t SZ_Q   = (size_t)Bb * NQn * Dn;   // 131072
  constexpr size_t SZ_S   = (size_t)Bb * NSn * Dn;   // 524288
  constexpr size_t SZ_FFH = (size_t)Bb * NQn * FFNn; // 524288

  float* qSb  = ws;
  float* kSb  = qSb + SZ_Q;
  float* vSb  = kSb + SZ_Q;
  float* oSb  = vSb + SZ_Q;
  float* soP  = oSb + SZ_Q;
  float* tgt2 = soP + SZ_Q;
  float* qCb  = tgt2 + SZ_Q;
  float* kCb  = qCb + SZ_Q;
  float* vCb  = kCb + SZ_S;
  float* oCb  = vCb + SZ_S;
  float* coP  = oCb + SZ_Q;
  float* tgt3 = coP + SZ_Q;
  float* ffh  = tgt3 + SZ_Q;
  float* part = ffh + SZ_FFH;           // 4 * SZ_Q
  float* tsb  = part + 4 * SZ_Q;
  float* Stab = tsb + RPEn;
  float* Btab = Stab + (RPEn + 1) * Hn;
  float* biasb = Btab + (RPEn + 1) * Hn;

  // Flash split partials overlay scratch with disjoint live ranges:
  // po reuses part (needed only after combine); pm/pl reuse ffh (FFN1 later).
  float* po = part;
  float* pm = ffh;
  float* pl = ffh + 16384;

  const int MQ = Bb * NQn;  // 512

  // 1. prep: cpb tables + self QKV + cross KV (all independent)
  prep_kernel<<<dim3(96 + 256 + 1), dim3(512), 0, stream>>>(
      qSb, kSb, vSb, kCb, vCb, tgt, qpos, src, spe, ipw, ipb,
      kw, kb, vw, vb, cpbw1, cpbb1, cpbw2, tsb, Stab, Btab);

  // 2. materialize cross-attn bias (search once per (b,q,k), 8 heads)
  bias_kernel<<<dim3(Bb * NQn), dim3(256), 0, stream>>>(
      biasb, rel, pad, tsb, Stab, Btab);

  // 3. self attention (fused flash, unsplit -> direct output)
  flash_kernel<<<dim3(NQn / 8, Bb * Hn, 1), dim3(256), 0, stream>>>(
      oSb, qSb, kSb, vSb, nullptr, NQn, po, pm, pl);

  // 4. self out-proj
  gemm32_kernel<<<dim3(Dn / 32, MQ / 32, 1), dim3(256), 0, stream>>>(
      soP, oSb, nullptr, outw, outb, Dn, Dn, Dn, 1.f);

  // 5. tgt2 = LN2(tgt + soP)
  add_ln_kernel<<<dim3(MQ), dim3(256), 0, stream>>>(tgt2, tgt, soP, ln2g, ln2b);

  // 6. cross q
  gemm32_kernel<<<dim3(Dn / 32, MQ / 32, 1), dim3(256), 0, stream>>>(
      qCb, tgt2, qpos, qw, qb, Dn, Dn, Dn, SCALEf);

  // 7. cross attention, key-split x4 (flash-decoding) -> partials
  flash_kernel<<<dim3(NQn / 8, Bb * Hn, 4), dim3(256), 0, stream>>>(
      oCb, qCb, kCb, vCb, biasb, NSn, po, pm, pl);

  // 8. combine split partials -> oCb
  flash_combine<<<dim3(Bb * Hn * NQn / 8), dim3(256), 0, stream>>>(
      oCb, po, pm, pl, 4);

  // 9. cross out-proj
  gemm32_kernel<<<dim3(Dn / 32, MQ / 32, 1), dim3(256), 0, stream>>>(
      coP, oCb, nullptr, projw, projb, Dn, Dn, Dn, 1.f);

  // 10. tgt3 = LN1(tgt2 + coP)
  add_ln_kernel<<<dim3(MQ), dim3(256), 0, stream>>>(tgt3, tgt2, coP, ln1g, ln1b);

  // 11. FFN1 (relu)
  gemm64_kernel<<<dim3(FFNn / 64, MQ / 64), dim3(512), 0, stream>>>(
      ffh, tgt3, ff1w, ff1b, Dn, FFNn, 1);

  // 12. FFN2 split-K x4 -> partials
  gemm32_kernel<<<dim3(Dn / 32, MQ / 32, 4), dim3(256), 0, stream>>>(
      part, ffh, nullptr, ff2w, nullptr, Dn, 256, FFNn, 1.f);

  // 13. out = LN3(tgt3 + sum(part) + ff2b)
  reduce_ln_kernel<<<dim3(MQ), dim3(256), 0, stream>>>(
      out, part, ff2b, tgt3, ln3g, ln3b);
}

// Round 6
// 165.624 us; speedup vs baseline: 4.6177x; 1.0006x over previous
//
#include <hip/hip_runtime.h>
#include <hip/hip_bf16.h>
#include <math.h>

#define Bb 2
#define NQn 256
#define NSn 1024
#define Dn 256
#define Hn 8
#define DHn 32
#define FFNn 1024
#define RPEn 512
#define SCALEf 0.17677669529663687f
#define EPSf 1e-5f

// ---------------------------------------------------------------------------
// gemm64 body: 64x64 tile, 512 threads, K-step 32, float4 loads, reg prefetch.
// ---------------------------------------------------------------------------
__device__ __forceinline__ void gemm64_body(
    float* __restrict__ C, int ldc,
    const float* __restrict__ A, const float* __restrict__ A2, int ld,
    const float* __restrict__ W, const float* __restrict__ bias,
    int K, int bm, int bnC, int bnW, float scale, int do_relu,
    float (*As)[33], float (*WsT)[68])
{
  const int tid = threadIdx.x;
  const int tx = tid & 15, ty = tid >> 4;       // ty 0..31
  const int lr = tid >> 3, lc = (tid & 7) * 4;  // staging coords
  float4 ra, rw;
  {
    ra = *(const float4*)(A + (size_t)(bm + lr) * ld + lc);
    if (A2) {
      float4 t = *(const float4*)(A2 + (size_t)(bm + lr) * ld + lc);
      ra.x += t.x; ra.y += t.y; ra.z += t.z; ra.w += t.w;
    }
    rw = *(const float4*)(W + (size_t)(bnW + lr) * ld + lc);
  }
  float acc[2][4] = {};
  for (int k0 = 0; k0 < K; k0 += 32) {
    As[lr][lc] = ra.x; As[lr][lc + 1] = ra.y;
    As[lr][lc + 2] = ra.z; As[lr][lc + 3] = ra.w;
    WsT[lc][lr] = rw.x; WsT[lc + 1][lr] = rw.y;
    WsT[lc + 2][lr] = rw.z; WsT[lc + 3][lr] = rw.w;
    __syncthreads();
    if (k0 + 32 < K) {
      ra = *(const float4*)(A + (size_t)(bm + lr) * ld + k0 + 32 + lc);
      if (A2) {
        float4 t = *(const float4*)(A2 + (size_t)(bm + lr) * ld + k0 + 32 + lc);
        ra.x += t.x; ra.y += t.y; ra.z += t.z; ra.w += t.w;
      }
      rw = *(const float4*)(W + (size_t)(bnW + lr) * ld + k0 + 32 + lc);
    }
#pragma unroll
    for (int k = 0; k < 32; ++k) {
      float a0 = As[ty][k], a1 = As[ty + 32][k];
      float4 w = *(const float4*)&WsT[k][tx * 4];
      acc[0][0] += a0 * w.x; acc[0][1] += a0 * w.y;
      acc[0][2] += a0 * w.z; acc[0][3] += a0 * w.w;
      acc[1][0] += a1 * w.x; acc[1][1] += a1 * w.y;
      acc[1][2] += a1 * w.z; acc[1][3] += a1 * w.w;
    }
    __syncthreads();
  }
#pragma unroll
  for (int i = 0; i < 2; ++i) {
    int m = bm + ty + i * 32;
#pragma unroll
    for (int j = 0; j < 4; ++j) {
      float v = acc[i][j];
      if (bias) v += bias[bnW + tx * 4 + j];
      v *= scale;
      if (do_relu) v = fmaxf(v, 0.f);
      C[(size_t)m * ldc + bnC + tx * 4 + j] = v;
    }
  }
}

// ---------------------------------------------------------------------------
// prep: fused build_cpb (1 block) + self QKV GEMM (96 blocks) + cross KV GEMM
// (256 blocks). 512 threads/block.
// ---------------------------------------------------------------------------
__global__ __launch_bounds__(512) void prep_kernel(
    float* __restrict__ qSb, float* __restrict__ kSb, float* __restrict__ vSb,
    float* __restrict__ kCb, float* __restrict__ vCb,
    const float* __restrict__ tgt, const float* __restrict__ qpos,
    const float* __restrict__ src, const float* __restrict__ spe,
    const float* __restrict__ ipw, const float* __restrict__ ipb,
    const float* __restrict__ kw, const float* __restrict__ kb,
    const float* __restrict__ vw, const float* __restrict__ vb,
    const float* __restrict__ w1p, const float* __restrict__ b1p,
    const float* __restrict__ w2p,
    float* __restrict__ tout, float* __restrict__ Stab, float* __restrict__ Btab)
{
  __shared__ float smem[4288];  // As 64*33=2112 + WsT 32*68=2176
  const int bx = blockIdx.x;
  const int tid = threadIdx.x;
  if (bx < 96) {
    float (*As)[33] = (float(*)[33])smem;
    float (*WsT)[68] = (float(*)[68])(smem + 2112);
    int my = bx & 7, nx = bx >> 3;
    int sec = nx >> 2;
    float* C = sec == 0 ? qSb : (sec == 1 ? kSb : vSb);
    gemm64_body(C, Dn, tgt, sec < 2 ? qpos : nullptr, Dn, ipw, ipb,
                Dn, my * 64, (nx & 3) * 64, nx * 64,
                sec == 0 ? SCALEf : 1.f, 0, As, WsT);
    return;
  }
  if (bx < 96 + 256) {
    float (*As)[33] = (float(*)[33])smem;
    float (*WsT)[68] = (float(*)[68])(smem + 2112);
    int idx = bx - 96;
    int my = idx & 31, nx = idx >> 5;
    int sec = nx >> 2;
    gemm64_body(sec ? vCb : kCb, Dn, src, sec ? nullptr : spe, Dn,
                sec ? vw : kw, sec ? vb : kb,
                Dn, my * 64, (nx & 3) * 64, (nx & 3) * 64, 1.f, 0, As, WsT);
    return;
  }
  // ---- cpb piecewise-linear table build (verified rounds 1-5) ----
  float* key = smem;
  int* pidx = (int*)(smem + 512);
  float* w1s = smem + 1024;
  float* b1s = smem + 1536;
  {
    float w = w1p[tid], bb = b1p[tid];
    key[tid] = (w != 0.f) ? (-bb / w) : 3.0e38f;
    pidx[tid] = tid;
  }
  __syncthreads();
  for (int k = 2; k <= RPEn; k <<= 1) {
    for (int j = k >> 1; j > 0; j >>= 1) {
      int ixj = tid ^ j;
      if (ixj > tid) {
        float a = key[tid], c = key[ixj];
        bool asc = ((tid & k) == 0);
        bool sw = asc ? (a > c) : (a < c);
        if (sw) {
          key[tid] = c; key[ixj] = a;
          int tmp = pidx[tid]; pidx[tid] = pidx[ixj]; pidx[ixj] = tmp;
        }
      }
      __syncthreads();
    }
  }
  w1s[tid] = w1p[pidx[tid]];
  b1s[tid] = b1p[pidx[tid]];
  tout[tid] = key[tid];
  __syncthreads();
  const int lane = tid & 63;
  const int h = tid >> 6;
  const int j0 = lane * 8;
  float sp[8], bp[8], sn[8], bn[8];
  float csp = 0.f, cbp = 0.f, csn = 0.f, cbn = 0.f, ccc = 0.f;
#pragma unroll
  for (int e = 0; e < 8; ++e) {
    int j = j0 + e;
    float w = w1s[j], b = b1s[j];
    float c = w2p[h * RPEn + pidx[j]];
    sp[e] = csp; bp[e] = cbp; sn[e] = csn; bn[e] = cbn;
    if (w > 0.f)      { csp += w * c; cbp += b * c; }
    else if (w < 0.f) { csn += w * c; cbn += b * c; }
    else              { ccc += fmaxf(b, 0.f) * c; }
  }
  float isp = csp, ibp = cbp, isn = csn, ibn = cbn, icc = ccc;
#pragma unroll
  for (int d = 1; d < 64; d <<= 1) {
    float t0 = __shfl_up(isp, d);
    float t1 = __shfl_up(ibp, d);
    float t2 = __shfl_up(isn, d);
    float t3 = __shfl_up(ibn, d);
    if (lane >= d) { isp += t0; ibp += t1; isn += t2; ibn += t3; }
    icc += __shfl_xor(icc, d);
  }
  const float tsn = __shfl(isn, 63);
  const float tbn = __shfl(ibn, 63);
  const float esp = isp - csp, ebp = ibp - cbp;
  const float esn = isn - csn, ebn = ibn - cbn;
#pragma unroll
  for (int e = 0; e < 8; ++e) {
    int j = j0 + e;
    Stab[j * Hn + h] = (esp + sp[e]) + (tsn - (esn + sn[e]));
    Btab[j * Hn + h] = (ebp + bp[e]) + (tbn - (ebn + bn[e])) + icc;
  }
  if (lane == 63) {
    Stab[RPEn * Hn + h] = isp;
    Btab[RPEn * Hn + h] = ibp + icc;
  }
}

// ---------------------------------------------------------------------------
// bias_kernel: materialize bias[b,h,q,k] = Sh[lo]*m + Bh[lo] - 100*pad.
// Binary search depends only on (b,q,k) -> done ONCE, applied to 8 heads.
// ---------------------------------------------------------------------------
__global__ __launch_bounds__(256) void bias_kernel(
    float* __restrict__ biasb, const float* __restrict__ rel,
    const float* __restrict__ pad, const float* __restrict__ tsg,
    const float* __restrict__ Stabg, const float* __restrict__ Btabg)
{
  __shared__ float ts[RPEn];
  __shared__ float Sh[(RPEn + 1) * Hn];
  __shared__ float Bh[(RPEn + 1) * Hn];
  const int tid = threadIdx.x;
  const int b = blockIdx.x >> 8, q = blockIdx.x & 255;
  ts[tid] = tsg[tid];
  ts[tid + 256] = tsg[tid + 256];
  for (int i = tid; i < (RPEn + 1) * Hn; i += 256) {
    Sh[i] = Stabg[i];
    Bh[i] = Btabg[i];
  }
  __syncthreads();
#pragma unroll
  for (int j = 0; j < 4; ++j) {
    const int k = tid + j * 256;
    const float m = rel[((size_t)b * NQn + q) * NSn + k];
    const float padv = -100.f * pad[b * NSn + k];
    int lo = 0, hi = RPEn;
#pragma unroll
    for (int it = 0; it < 9; ++it) {
      int mid = (lo + hi) >> 1;
      if (ts[mid] < m) lo = mid + 1; else hi = mid;
    }
#pragma unroll
    for (int h = 0; h < Hn; ++h) {
      biasb[(((size_t)(b * Hn + h)) * NQn + q) * NSn + k] =
          Sh[lo * Hn + h] * m + Bh[lo * Hn + h] + padv;
    }
  }
}

// ---------------------------------------------------------------------------
// Flash attention, double-buffered (T14/G15 async-stage split):
// prologue loads chunk 0 into regs; each iter writes regs->LDS[cur], ONE
// __syncthreads, issues chunk c+1 global loads (fly under compute), computes
// from LDS[cur]. Write-after-read across waves is safe: writes target the
// alternate buffer, whose last readers all passed the previous barrier.
// grid (NQ/8, B*H), 256 threads = (r 0..7, kc 0..31). 73 KB LDS -> 2 blk/CU,
// 512 blocks fully resident in one round.
// ---------------------------------------------------------------------------
__global__ __launch_bounds__(256) void flash_kernel(
    float* __restrict__ O, const float* __restrict__ Q,
    const float* __restrict__ K, const float* __restrict__ V,
    const float* __restrict__ biasb, int NK)
{
  __shared__ float4 Ks[2][1024];
  __shared__ float4 Vs[2][1024];
  __shared__ float Bs[2][1024];
  __shared__ float4 Qs[64];
  const int bh = blockIdx.y, b = bh >> 3, h = bh & 7;
  const int q0 = blockIdx.x * 8;
  const int tid = threadIdx.x;
  const float4* Kg = (const float4*)K;
  const float4* Vg = (const float4*)V;
  const int sdd = tid & 7, sk = tid >> 3;  // staging coords (k-major, 8 f4/key)
  if (tid < 64) {
    int rr = tid >> 3, d4 = tid & 7;
    Qs[tid] = ((const float4*)Q)[(size_t)(b * NQn + q0 + rr) * 64 + h * 8 + d4];
  }
  __syncthreads();
  const int r = tid >> 5, kc = tid & 31;
  float4 q[8];
#pragma unroll
  for (int dd = 0; dd < 8; ++dd) q[dd] = Qs[r * 8 + dd];
  float4 o[8] = {};
  float m_run = -3.0e38f, l_run = 0.f;
  const int nchunk = NK >> 7;

  float4 rk[4], rv[4], rb;
  // prologue: issue chunk-0 loads
#pragma unroll
  for (int u = 0; u < 4; ++u) {
    size_t g = (size_t)(b * NK + sk + u * 32) * 64 + h * 8 + sdd;
    rk[u] = Kg[g];
    rv[u] = Vg[g];
  }
  if (biasb)
    rb = ((const float4*)(biasb + ((size_t)bh * NQn + q0 + r) * NK))[kc];

  for (int c = 0; c < nchunk; ++c) {
    const int cur = c & 1;
    // write staged regs -> LDS[cur]
#pragma unroll
    for (int u = 0; u < 4; ++u) {
      int k = sk + u * 32;
      Ks[cur][sdd * 128 + (k ^ sdd)] = rk[u];
      Vs[cur][sdd * 128 + (k ^ sdd)] = rv[u];
    }
    if (biasb) ((float4*)Bs[cur])[tid] = rb;
    __syncthreads();
    // issue next-chunk loads (hide under compute)
    if (c + 1 < nchunk) {
      const int kb1 = (c + 1) * 128;
#pragma unroll
      for (int u = 0; u < 4; ++u) {
        size_t g = (size_t)(b * NK + kb1 + sk + u * 32) * 64 + h * 8 + sdd;
        rk[u] = Kg[g];
        rv[u] = Vg[g];
      }
      if (biasb)
        rb = ((const float4*)(biasb + ((size_t)bh * NQn + q0 + r) * NK + kb1))[kc];
    }
    // compute on LDS[cur]
    float s[4];
    float cmax = -3.0e38f;
#pragma unroll
    for (int j = 0; j < 4; ++j) {
      const int k = kc + j * 32;
      float4 a4 = {0.f, 0.f, 0.f, 0.f};
#pragma unroll
      for (int dd = 0; dd < 8; ++dd) {
        float4 kk = Ks[cur][dd * 128 + (k ^ dd)];
        a4.x += q[dd].x * kk.x; a4.y += q[dd].y * kk.y;
        a4.z += q[dd].z * kk.z; a4.w += q[dd].w * kk.w;
      }
      float sv = (a4.x + a4.y) + (a4.z + a4.w);
      if (biasb) sv += Bs[cur][r * 128 + k];
      s[j] = sv;
      cmax = fmaxf(cmax, sv);
    }
#pragma unroll
    for (int off = 1; off < 32; off <<= 1) cmax = fmaxf(cmax, __shfl_xor(cmax, off));
    const float m_new = fmaxf(m_run, cmax);
    const float f = __expf(m_run - m_new);
    float lsum = 0.f;
#pragma unroll
    for (int j = 0; j < 4; ++j) { s[j] = __expf(s[j] - m_new); lsum += s[j]; }
#pragma unroll
    for (int off = 1; off < 32; off <<= 1) lsum += __shfl_xor(lsum, off);
    l_run = l_run * f + lsum;
    m_run = m_new;
#pragma unroll
    for (int dd = 0; dd < 8; ++dd) {
      o[dd].x *= f; o[dd].y *= f; o[dd].z *= f; o[dd].w *= f;
    }
#pragma unroll
    for (int j = 0; j < 4; ++j) {
      const int k = kc + j * 32;
      const float p = s[j];
#pragma unroll
      for (int dd = 0; dd < 8; ++dd) {
        float4 vv = Vs[cur][dd * 128 + (k ^ dd)];
        o[dd].x += p * vv.x; o[dd].y += p * vv.y;
        o[dd].z += p * vv.z; o[dd].w += p * vv.w;
      }
    }
    __syncthreads();
  }
#pragma unroll
  for (int off = 1; off < 32; off <<= 1) {
#pragma unroll
    for (int dd = 0; dd < 8; ++dd) {
      o[dd].x += __shfl_xor(o[dd].x, off);
      o[dd].y += __shfl_xor(o[dd].y, off);
      o[dd].z += __shfl_xor(o[dd].z, off);
      o[dd].w += __shfl_xor(o[dd].w, off);
    }
  }
  if (kc == 0) {
    const float inv = 1.f / l_run;
#pragma unroll
    for (int dd = 0; dd < 8; ++dd) {
      float4 w = o[dd];
      w.x *= inv; w.y *= inv; w.z *= inv; w.w *= inv;
      ((float4*)O)[(size_t)(b * NQn + q0 + r) * 64 + h * 8 + dd] = w;
    }
  }
}

// ---------------------------------------------------------------------------
// gemm64 standalone (FFN1): grid (N/64, M/64), 512 threads.
// ---------------------------------------------------------------------------
__global__ __launch_bounds__(512) void gemm64_kernel(
    float* __restrict__ C, const float* __restrict__ A,
    const float* __restrict__ W, const float* __restrict__ bias,
    int ld, int ldc, int do_relu)
{
  __shared__ float smem[4288];
  float (*As)[33] = (float(*)[33])smem;
  float (*WsT)[68] = (float(*)[68])(smem + 2112);
  gemm64_body(C, ldc, A, nullptr, ld, W, bias, ld,
              blockIdx.y * 64, blockIdx.x * 64, blockIdx.x * 64, 1.f, do_relu,
              As, WsT);
}

// ---------------------------------------------------------------------------
// gemm32: 32x32 tile, 256 threads, 2x2/thread, K-step 32, float4 staging with
// register prefetch. Split-K via blockIdx.z (partials at kz*M*N).
// ---------------------------------------------------------------------------
__global__ __launch_bounds__(256) void gemm32_kernel(
    float* __restrict__ C, const float* __restrict__ A, const float* __restrict__ A2,
    const float* __restrict__ W, const float* __restrict__ bias,
    int N, int Kchunk, int Ktot, float scale)
{
  __shared__ float As[32][33];
  __shared__ float Ws[32][33];
  const int bm = blockIdx.y * 32, bn = blockIdx.x * 32;
  const int kz = blockIdx.z;
  const int M = gridDim.y * 32;
  float* Cp = C + (size_t)kz * M * N;
  const int tid = threadIdx.x;
  const int tx = tid & 15, ty = tid >> 4;
  const int lr = tid >> 3, lc = (tid & 7) * 4;
  float acc[2][2] = {};
  const int k00 = kz * Kchunk;
  float4 av, wv;
  {
    av = *(const float4*)(A + (size_t)(bm + lr) * Ktot + k00 + lc);
    if (A2) {
      float4 bv = *(const float4*)(A2 + (size_t)(bm + lr) * Ktot + k00 + lc);
      av.x += bv.x; av.y += bv.y; av.z += bv.z; av.w += bv.w;
    }
    wv = *(const float4*)(W + (size_t)(bn + lr) * Ktot + k00 + lc);
  }
  for (int k0 = k00; k0 < k00 + Kchunk; k0 += 32) {
    As[lr][lc] = av.x; As[lr][lc + 1] = av.y; As[lr][lc + 2] = av.z; As[lr][lc + 3] = av.w;
    Ws[lr][lc] = wv.x; Ws[lr][lc + 1] = wv.y; Ws[lr][lc + 2] = wv.z; Ws[lr][lc + 3] = wv.w;
    __syncthreads();
    if (k0 + 32 < k00 + Kchunk) {
      av = *(const float4*)(A + (size_t)(bm + lr) * Ktot + k0 + 32 + lc);
      if (A2) {
        float4 bv = *(const float4*)(A2 + (size_t)(bm + lr) * Ktot + k0 + 32 + lc);
        av.x += bv.x; av.y += bv.y; av.z += bv.z; av.w += bv.w;
      }
      wv = *(const float4*)(W + (size_t)(bn + lr) * Ktot + k0 + 32 + lc);
    }
#pragma unroll
    for (int k = 0; k < 32; ++k) {
      float a0 = As[ty * 2][k], a1 = As[ty * 2 + 1][k];
      float w0 = Ws[tx * 2][k], w1 = Ws[tx * 2 + 1][k];
      acc[0][0] += a0 * w0; acc[0][1] += a0 * w1;
      acc[1][0] += a1 * w0; acc[1][1] += a1 * w1;
    }
    __syncthreads();
  }
#pragma unroll
  for (int i = 0; i < 2; ++i) {
    int m = bm + ty * 2 + i;
#pragma unroll
    for (int j = 0; j < 2; ++j) {
      int n = bn + tx * 2 + j;
      float v = acc[i][j];
      if (bias) v += bias[n];
      Cp[(size_t)m * N + n] = v * scale;
    }
  }
}

// ---------------------------------------------------------------------------
// out = LayerNorm(x1 + x2) * g + b.  grid: rows, block = 256 = D.
// ---------------------------------------------------------------------------
__global__ __launch_bounds__(256) void add_ln_kernel(
    float* __restrict__ out, const float* __restrict__ x1, const float* __restrict__ x2,
    const float* __restrict__ g, const float* __restrict__ bt)
{
  const int row = blockIdx.x;
  const int t = threadIdx.x;
  const float v = x1[(size_t)row * Dn + t] + x2[(size_t)row * Dn + t];
  float s = v, s2 = v * v;
#pragma unroll
  for (int off = 32; off > 0; off >>= 1) {
    s += __shfl_down(s, off);
    s2 += __shfl_down(s2, off);
  }
  __shared__ float rs[4], rs2[4], fin[2];
  const int lane = t & 63, wid = t >> 6;
  if (lane == 0) { rs[wid] = s; rs2[wid] = s2; }
  __syncthreads();
  if (t == 0) {
    float a = rs[0] + rs[1] + rs[2] + rs[3];
    float a2 = rs2[0] + rs2[1] + rs2[2] + rs2[3];
    float mean = a * (1.f / Dn);
    float var = a2 * (1.f / Dn) - mean * mean;
    fin[0] = mean;
    fin[1] = rsqrtf(var + EPSf);
  }
  __syncthreads();
  out[(size_t)row * Dn + t] = (v - fin[0]) * fin[1] * g[t] + bt[t];
}

// ---------------------------------------------------------------------------
// out = LayerNorm(resid + sum_{kz<4} part[kz] + bias) * g + b (split-K reduce)
// ---------------------------------------------------------------------------
__global__ __launch_bounds__(256) void reduce_ln_kernel(
    float* __restrict__ out, const float* __restrict__ part,
    const float* __restrict__ bias, const float* __restrict__ resid,
    const float* __restrict__ g, const float* __restrict__ bt)
{
  const int row = blockIdx.x;
  const int t = threadIdx.x;
  const size_t idx = (size_t)row * Dn + t;
  const size_t STR = (size_t)Bb * NQn * Dn;
  float v = part[idx] + part[idx + STR] + part[idx + 2 * STR] + part[idx + 3 * STR]
          + bias[t] + resid[idx];
  float s = v, s2 = v * v;
#pragma unroll
  for (int off = 32; off > 0; off >>= 1) {
    s += __shfl_down(s, off);
    s2 += __shfl_down(s2, off);
  }
  __shared__ float rs[4], rs2[4], fin[2];
  const int lane = t & 63, wid = t >> 6;
  if (lane == 0) { rs[wid] = s; rs2[wid] = s2; }
  __syncthreads();
  if (t == 0) {
    float a = rs[0] + rs[1] + rs[2] + rs[3];
    float a2 = rs2[0] + rs2[1] + rs2[2] + rs2[3];
    float mean = a * (1.f / Dn);
    float var = a2 * (1.f / Dn) - mean * mean;
    fin[0] = mean;
    fin[1] = rsqrtf(var + EPSf);
  }
  __syncthreads();
  out[idx] = (v - fin[0]) * fin[1] * g[t] + bt[t];
}

extern "C" void kernel_launch(void* const* d_in, const int* in_sizes, int n_in,
                              void* d_out, int out_size, void* d_ws, size_t ws_size,
                              hipStream_t stream)
{
  const float* tgt   = (const float*)d_in[0];
  const float* qpos  = (const float*)d_in[1];
  const float* src   = (const float*)d_in[2];
  const float* spe   = (const float*)d_in[3];
  const float* pad   = (const float*)d_in[4];
  const float* rel   = (const float*)d_in[5];
  const float* qw    = (const float*)d_in[6];
  const float* qb    = (const float*)d_in[7];
  const float* kw    = (const float*)d_in[8];
  const float* kb    = (const float*)d_in[9];
  const float* vw    = (const float*)d_in[10];
  const float* vb    = (const float*)d_in[11];
  const float* projw = (const float*)d_in[12];
  const float* projb = (const float*)d_in[13];
  const float* cpbw1 = (const float*)d_in[14];
  const float* cpbb1 = (const float*)d_in[15];
  const float* cpbw2 = (const float*)d_in[16];
  const float* ipw   = (const float*)d_in[17];
  const float* ipb   = (const float*)d_in[18];
  const float* outw  = (const float*)d_in[19];
  const float* outb  = (const float*)d_in[20];
  const float* ln1g  = (const float*)d_in[21];
  const float* ln1b  = (const float*)d_in[22];
  const float* ln2g  = (const float*)d_in[23];
  const float* ln2b  = (const float*)d_in[24];
  const float* ln3g  = (const float*)d_in[25];
  const float* ln3b  = (const float*)d_in[26];
  const float* ff1w  = (const float*)d_in[27];
  const float* ff1b  = (const float*)d_in[28];
  const float* ff2w  = (const float*)d_in[29];
  const float* ff2b  = (const float*)d_in[30];
  float* out = (float*)d_out;
  float* ws = (float*)d_ws;

  constexpr size_t SZ_Q   = (size_t)Bb * NQn * Dn;   // 131072
  constexpr size_t SZ_S   = (size_t)Bb * NSn * Dn;   // 524288
  constexpr size_t SZ_FFH = (size_t)Bb * NQn * FFNn; // 524288

  float* qSb  = ws;
  float* kSb  = qSb + SZ_Q;
  float* vSb  = kSb + SZ_Q;
  float* oSb  = vSb + SZ_Q;
  float* soP  = oSb + SZ_Q;
  float* tgt2 = soP + SZ_Q;
  float* qCb  = tgt2 + SZ_Q;
  float* kCb  = qCb + SZ_Q;
  float* vCb  = kCb + SZ_S;
  float* oCb  = vCb + SZ_S;
  float* coP  = oCb + SZ_Q;
  float* tgt3 = coP + SZ_Q;
  float* ffh  = tgt3 + SZ_Q;
  float* part = ffh + SZ_FFH;           // 4 * SZ_Q
  float* tsb  = part + 4 * SZ_Q;
  float* Stab = tsb + RPEn;
  float* Btab = Stab + (RPEn + 1) * Hn;
  float* biasb = Btab + (RPEn + 1) * Hn;

  const int MQ = Bb * NQn;  // 512

  // 1. prep: cpb tables + self QKV + cross KV (all independent)
  prep_kernel<<<dim3(96 + 256 + 1), dim3(512), 0, stream>>>(
      qSb, kSb, vSb, kCb, vCb, tgt, qpos, src, spe, ipw, ipb,
      kw, kb, vw, vb, cpbw1, cpbb1, cpbw2, tsb, Stab, Btab);

  // 2. materialize cross-attn bias (search once per (b,q,k), 8 heads)
  bias_kernel<<<dim3(Bb * NQn), dim3(256), 0, stream>>>(
      biasb, rel, pad, tsb, Stab, Btab);

  // 3. self attention (double-buffered flash)
  flash_kernel<<<dim3(NQn / 8, Bb * Hn), dim3(256), 0, stream>>>(
      oSb, qSb, kSb, vSb, nullptr, NQn);

  // 4. self out-proj
  gemm32_kernel<<<dim3(Dn / 32, MQ / 32, 1), dim3(256), 0, stream>>>(
      soP, oSb, nullptr, outw, outb, Dn, Dn, Dn, 1.f);

  // 5. tgt2 = LN2(tgt + soP)
  add_ln_kernel<<<dim3(MQ), dim3(256), 0, stream>>>(tgt2, tgt, soP, ln2g, ln2b);

  // 6. cross q
  gemm32_kernel<<<dim3(Dn / 32, MQ / 32, 1), dim3(256), 0, stream>>>(
      qCb, tgt2, qpos, qw, qb, Dn, Dn, Dn, SCALEf);

  // 7. cross attention (double-buffered flash + staged bias)
  flash_kernel<<<dim3(NQn / 8, Bb * Hn), dim3(256), 0, stream>>>(
      oCb, qCb, kCb, vCb, biasb, NSn);

  // 8. cross out-proj
  gemm32_kernel<<<dim3(Dn / 32, MQ / 32, 1), dim3(256), 0, stream>>>(
      coP, oCb, nullptr, projw, projb, Dn, Dn, Dn, 1.f);

  // 9. tgt3 = LN1(tgt2 + coP)
  add_ln_kernel<<<dim3(MQ), dim3(256), 0, stream>>>(tgt3, tgt2, coP, ln1g, ln1b);

  // 10. FFN1 (relu)
  gemm64_kernel<<<dim3(FFNn / 64, MQ / 64), dim3(512), 0, stream>>>(
      ffh, tgt3, ff1w, ff1b, Dn, FFNn, 1);

  // 11. FFN2 split-K x4 -> partials
  gemm32_kernel<<<dim3(Dn / 32, MQ / 32, 4), dim3(256), 0, stream>>>(
      part, ffh, nullptr, ff2w, nullptr, Dn, 256, FFNn, 1.f);

  // 12. out = LN3(tgt3 + sum(part) + ff2b)
  reduce_ln_kernel<<<dim3(MQ), dim3(256), 0, stream>>>(
      out, part, ff2b, tgt3, ln3g, ln3b);
}

// Round 7
// 139.157 us; speedup vs baseline: 5.4960x; 1.1902x over previous
//
#include <hip/hip_runtime.h>
#include <hip/hip_bf16.h>
#include <math.h>

#define Bb 2
#define NQn 256
#define NSn 1024
#define Dn 256
#define Hn 8
#define DHn 32
#define FFNn 1024
#define RPEn 512
#define SCALEf 0.17677669529663687f
#define EPSf 1e-5f

// async global->LDS, 16B per lane. LDS dest must be linear in lane order
// (wave-uniform base + lane*16); global src is per-lane (pre-swizzled).
#define GLDS16(g, l)                                                         \
  __builtin_amdgcn_global_load_lds(                                          \
      (const __attribute__((address_space(1))) void*)(const void*)(g),       \
      (__attribute__((address_space(3))) void*)(void*)(l), 16, 0, 0)

// ---------------------------------------------------------------------------
// gemm64 body: 64x64 tile, 512 threads, K-step 32, float4 loads, reg prefetch.
// ---------------------------------------------------------------------------
__device__ __forceinline__ void gemm64_body(
    float* __restrict__ C, int ldc,
    const float* __restrict__ A, const float* __restrict__ A2, int ld,
    const float* __restrict__ W, const float* __restrict__ bias,
    int K, int bm, int bnC, int bnW, float scale, int do_relu,
    float (*As)[33], float (*WsT)[68])
{
  const int tid = threadIdx.x;
  const int tx = tid & 15, ty = tid >> 4;       // ty 0..31
  const int lr = tid >> 3, lc = (tid & 7) * 4;  // staging coords
  float4 ra, rw;
  {
    ra = *(const float4*)(A + (size_t)(bm + lr) * ld + lc);
    if (A2) {
      float4 t = *(const float4*)(A2 + (size_t)(bm + lr) * ld + lc);
      ra.x += t.x; ra.y += t.y; ra.z += t.z; ra.w += t.w;
    }
    rw = *(const float4*)(W + (size_t)(bnW + lr) * ld + lc);
  }
  float acc[2][4] = {};
  for (int k0 = 0; k0 < K; k0 += 32) {
    As[lr][lc] = ra.x; As[lr][lc + 1] = ra.y;
    As[lr][lc + 2] = ra.z; As[lr][lc + 3] = ra.w;
    WsT[lc][lr] = rw.x; WsT[lc + 1][lr] = rw.y;
    WsT[lc + 2][lr] = rw.z; WsT[lc + 3][lr] = rw.w;
    __syncthreads();
    if (k0 + 32 < K) {
      ra = *(const float4*)(A + (size_t)(bm + lr) * ld + k0 + 32 + lc);
      if (A2) {
        float4 t = *(const float4*)(A2 + (size_t)(bm + lr) * ld + k0 + 32 + lc);
        ra.x += t.x; ra.y += t.y; ra.z += t.z; ra.w += t.w;
      }
      rw = *(const float4*)(W + (size_t)(bnW + lr) * ld + k0 + 32 + lc);
    }
#pragma unroll
    for (int k = 0; k < 32; ++k) {
      float a0 = As[ty][k], a1 = As[ty + 32][k];
      float4 w = *(const float4*)&WsT[k][tx * 4];
      acc[0][0] += a0 * w.x; acc[0][1] += a0 * w.y;
      acc[0][2] += a0 * w.z; acc[0][3] += a0 * w.w;
      acc[1][0] += a1 * w.x; acc[1][1] += a1 * w.y;
      acc[1][2] += a1 * w.z; acc[1][3] += a1 * w.w;
    }
    __syncthreads();
  }
#pragma unroll
  for (int i = 0; i < 2; ++i) {
    int m = bm + ty + i * 32;
#pragma unroll
    for (int j = 0; j < 4; ++j) {
      float v = acc[i][j];
      if (bias) v += bias[bnW + tx * 4 + j];
      v *= scale;
      if (do_relu) v = fmaxf(v, 0.f);
      C[(size_t)m * ldc + bnC + tx * 4 + j] = v;
    }
  }
}

// ---------------------------------------------------------------------------
// prep: fused build_cpb (1 block) + self QKV GEMM (96 blocks) + cross KV GEMM
// (256 blocks). 512 threads/block.
// ---------------------------------------------------------------------------
__global__ __launch_bounds__(512) void prep_kernel(
    float* __restrict__ qSb, float* __restrict__ kSb, float* __restrict__ vSb,
    float* __restrict__ kCb, float* __restrict__ vCb,
    const float* __restrict__ tgt, const float* __restrict__ qpos,
    const float* __restrict__ src, const float* __restrict__ spe,
    const float* __restrict__ ipw, const float* __restrict__ ipb,
    const float* __restrict__ kw, const float* __restrict__ kb,
    const float* __restrict__ vw, const float* __restrict__ vb,
    const float* __restrict__ w1p, const float* __restrict__ b1p,
    const float* __restrict__ w2p,
    float* __restrict__ tout, float* __restrict__ Stab, float* __restrict__ Btab)
{
  __shared__ float smem[4288];  // As 64*33=2112 + WsT 32*68=2176
  const int bx = blockIdx.x;
  const int tid = threadIdx.x;
  if (bx < 96) {
    float (*As)[33] = (float(*)[33])smem;
    float (*WsT)[68] = (float(*)[68])(smem + 2112);
    int my = bx & 7, nx = bx >> 3;
    int sec = nx >> 2;
    float* C = sec == 0 ? qSb : (sec == 1 ? kSb : vSb);
    gemm64_body(C, Dn, tgt, sec < 2 ? qpos : nullptr, Dn, ipw, ipb,
                Dn, my * 64, (nx & 3) * 64, nx * 64,
                sec == 0 ? SCALEf : 1.f, 0, As, WsT);
    return;
  }
  if (bx < 96 + 256) {
    float (*As)[33] = (float(*)[33])smem;
    float (*WsT)[68] = (float(*)[68])(smem + 2112);
    int idx = bx - 96;
    int my = idx & 31, nx = idx >> 5;
    int sec = nx >> 2;
    gemm64_body(sec ? vCb : kCb, Dn, src, sec ? nullptr : spe, Dn,
                sec ? vw : kw, sec ? vb : kb,
                Dn, my * 64, (nx & 3) * 64, (nx & 3) * 64, 1.f, 0, As, WsT);
    return;
  }
  // ---- cpb piecewise-linear table build (verified rounds 1-6) ----
  float* key = smem;
  int* pidx = (int*)(smem + 512);
  float* w1s = smem + 1024;
  float* b1s = smem + 1536;
  {
    float w = w1p[tid], bb = b1p[tid];
    key[tid] = (w != 0.f) ? (-bb / w) : 3.0e38f;
    pidx[tid] = tid;
  }
  __syncthreads();
  for (int k = 2; k <= RPEn; k <<= 1) {
    for (int j = k >> 1; j > 0; j >>= 1) {
      int ixj = tid ^ j;
      if (ixj > tid) {
        float a = key[tid], c = key[ixj];
        bool asc = ((tid & k) == 0);
        bool sw = asc ? (a > c) : (a < c);
        if (sw) {
          key[tid] = c; key[ixj] = a;
          int tmp = pidx[tid]; pidx[tid] = pidx[ixj]; pidx[ixj] = tmp;
        }
      }
      __syncthreads();
    }
  }
  w1s[tid] = w1p[pidx[tid]];
  b1s[tid] = b1p[pidx[tid]];
  tout[tid] = key[tid];
  __syncthreads();
  const int lane = tid & 63;
  const int h = tid >> 6;
  const int j0 = lane * 8;
  float sp[8], bp[8], sn[8], bn[8];
  float csp = 0.f, cbp = 0.f, csn = 0.f, cbn = 0.f, ccc = 0.f;
#pragma unroll
  for (int e = 0; e < 8; ++e) {
    int j = j0 + e;
    float w = w1s[j], b = b1s[j];
    float c = w2p[h * RPEn + pidx[j]];
    sp[e] = csp; bp[e] = cbp; sn[e] = csn; bn[e] = cbn;
    if (w > 0.f)      { csp += w * c; cbp += b * c; }
    else if (w < 0.f) { csn += w * c; cbn += b * c; }
    else              { ccc += fmaxf(b, 0.f) * c; }
  }
  float isp = csp, ibp = cbp, isn = csn, ibn = cbn, icc = ccc;
#pragma unroll
  for (int d = 1; d < 64; d <<= 1) {
    float t0 = __shfl_up(isp, d);
    float t1 = __shfl_up(ibp, d);
    float t2 = __shfl_up(isn, d);
    float t3 = __shfl_up(ibn, d);
    if (lane >= d) { isp += t0; ibp += t1; isn += t2; ibn += t3; }
    icc += __shfl_xor(icc, d);
  }
  const float tsn = __shfl(isn, 63);
  const float tbn = __shfl(ibn, 63);
  const float esp = isp - csp, ebp = ibp - cbp;
  const float esn = isn - csn, ebn = ibn - cbn;
#pragma unroll
  for (int e = 0; e < 8; ++e) {
    int j = j0 + e;
    Stab[j * Hn + h] = (esp + sp[e]) + (tsn - (esn + sn[e]));
    Btab[j * Hn + h] = (ebp + bp[e]) + (tbn - (ebn + bn[e])) + icc;
  }
  if (lane == 63) {
    Stab[RPEn * Hn + h] = isp;
    Btab[RPEn * Hn + h] = ibp + icc;
  }
}

// ---------------------------------------------------------------------------
// bias_kernel: materialize bias[b,h,q,k] = Sh[lo]*m + Bh[lo] - 100*pad.
// Binary search depends only on (b,q,k) -> done ONCE, applied to 8 heads.
// ---------------------------------------------------------------------------
__global__ __launch_bounds__(256) void bias_kernel(
    float* __restrict__ biasb, const float* __restrict__ rel,
    const float* __restrict__ pad, const float* __restrict__ tsg,
    const float* __restrict__ Stabg, const float* __restrict__ Btabg)
{
  __shared__ float ts[RPEn];
  __shared__ float Sh[(RPEn + 1) * Hn];
  __shared__ float Bh[(RPEn + 1) * Hn];
  const int tid = threadIdx.x;
  const int b = blockIdx.x >> 8, q = blockIdx.x & 255;
  ts[tid] = tsg[tid];
  ts[tid + 256] = tsg[tid + 256];
  for (int i = tid; i < (RPEn + 1) * Hn; i += 256) {
    Sh[i] = Stabg[i];
    Bh[i] = Btabg[i];
  }
  __syncthreads();
#pragma unroll
  for (int j = 0; j < 4; ++j) {
    const int k = tid + j * 256;
    const float m = rel[((size_t)b * NQn + q) * NSn + k];
    const float padv = -100.f * pad[b * NSn + k];
    int lo = 0, hi = RPEn;
#pragma unroll
    for (int it = 0; it < 9; ++it) {
      int mid = (lo + hi) >> 1;
      if (ts[mid] < m) lo = mid + 1; else hi = mid;
    }
#pragma unroll
    for (int h = 0; h < Hn; ++h) {
      biasb[(((size_t)(b * Hn + h)) * NQn + q) * NSn + k] =
          Sh[lo * Hn + h] * m + Bh[lo * Hn + h] + padv;
    }
  }
}

// ---------------------------------------------------------------------------
// Flash attention, double-buffered via global_load_lds (zero staging VGPRs):
// prologue stages chunk 0 -> barrier; each iter issues chunk c+1 gload_lds
// into buf^1 (flies under compute), computes chunk c from buf, barrier
// (compiler emits vmcnt(0) drain there). K/V swizzle realized on the GLOBAL
// source address; LDS dest linear in lane order (rule: both-sides-or-neither).
// grid (NQ/8, B*H), 256 threads = (r 0..7, kc 0..31). ~74 KB LDS -> 2 blk/CU.
// ---------------------------------------------------------------------------
__global__ __launch_bounds__(256, 2) void flash_kernel(
    float* __restrict__ O, const float* __restrict__ Q,
    const float* __restrict__ K, const float* __restrict__ V,
    const float* __restrict__ biasb, int NK)
{
  __shared__ float4 Ks[2][1024];
  __shared__ float4 Vs[2][1024];
  __shared__ float4 Bs[2][256];  // 8 rows x 128 floats
  __shared__ float4 Qs[64];
  const int bh = blockIdx.y, b = bh >> 3, h = bh & 7;
  const int q0 = blockIdx.x * 8;
  const int tid = threadIdx.x;
  const float4* Kg = (const float4*)K;
  const float4* Vg = (const float4*)V;
  const int r = tid >> 5, kc = tid & 31;
  if (tid < 64)
    Qs[tid] = ((const float4*)Q)[(size_t)(b * NQn + q0 + (tid >> 3)) * 64 +
                                 h * 8 + (tid & 7)];

  // stage chunk at kb0 into buffer buf (async, no VGPR round-trip)
  auto stage = [&](int buf, int kb0) {
#pragma unroll
    for (int u = 0; u < 4; ++u) {
      const int s = tid + u * 256;              // linear LDS slot (lane order)
      const int dd = s >> 7;
      const int k = (s & 127) ^ dd;             // inverse swizzle on source
      const size_t g = (size_t)(b * NK + kb0 + k) * 64 + h * 8 + dd;
      GLDS16(Kg + g, &Ks[buf][s]);
      GLDS16(Vg + g, &Vs[buf][s]);
    }
    if (biasb) {
      const float4* gb =
          (const float4*)(biasb + ((size_t)bh * NQn + q0 + r) * NK + kb0) + kc;
      GLDS16(gb, &Bs[buf][tid]);
    }
  };

  stage(0, 0);
  __syncthreads();  // drains vmcnt(0): chunk 0 + Qs ready

  float4 q[8];
#pragma unroll
  for (int dd = 0; dd < 8; ++dd) q[dd] = Qs[r * 8 + dd];
  float4 o[8] = {};
  float m_run = -3.0e38f, l_run = 0.f;
  const int nchunk = NK >> 7;

  for (int c = 0; c < nchunk; ++c) {
    const int cur = c & 1;
    if (c + 1 < nchunk) stage(cur ^ 1, (c + 1) * 128);  // prefetch in flight
    // compute on LDS[cur]
    float s[4];
    float cmax = -3.0e38f;
#pragma unroll
    for (int j = 0; j < 4; ++j) {
      const int k = kc + j * 32;
      float4 a4 = {0.f, 0.f, 0.f, 0.f};
#pragma unroll
      for (int dd = 0; dd < 8; ++dd) {
        float4 kk = Ks[cur][dd * 128 + (k ^ dd)];
        a4.x += q[dd].x * kk.x; a4.y += q[dd].y * kk.y;
        a4.z += q[dd].z * kk.z; a4.w += q[dd].w * kk.w;
      }
      float sv = (a4.x + a4.y) + (a4.z + a4.w);
      if (biasb) sv += ((const float*)Bs[cur])[r * 128 + k];
      s[j] = sv;
      cmax = fmaxf(cmax, sv);
    }
#pragma unroll
    for (int off = 1; off < 32; off <<= 1) cmax = fmaxf(cmax, __shfl_xor(cmax, off));
    const float m_new = fmaxf(m_run, cmax);
    const float f = __expf(m_run - m_new);
    float lsum = 0.f;
#pragma unroll
    for (int j = 0; j < 4; ++j) { s[j] = __expf(s[j] - m_new); lsum += s[j]; }
#pragma unroll
    for (int off = 1; off < 32; off <<= 1) lsum += __shfl_xor(lsum, off);
    l_run = l_run * f + lsum;
    m_run = m_new;
#pragma unroll
    for (int dd = 0; dd < 8; ++dd) {
      o[dd].x *= f; o[dd].y *= f; o[dd].z *= f; o[dd].w *= f;
    }
#pragma unroll
    for (int j = 0; j < 4; ++j) {
      const int k = kc + j * 32;
      const float p = s[j];
#pragma unroll
      for (int dd = 0; dd < 8; ++dd) {
        float4 vv = Vs[cur][dd * 128 + (k ^ dd)];
        o[dd].x += p * vv.x; o[dd].y += p * vv.y;
        o[dd].z += p * vv.z; o[dd].w += p * vv.w;
      }
    }
    __syncthreads();  // drains prefetch vmcnt + LDS reads before buffer reuse
  }
#pragma unroll
  for (int off = 1; off < 32; off <<= 1) {
#pragma unroll
    for (int dd = 0; dd < 8; ++dd) {
      o[dd].x += __shfl_xor(o[dd].x, off);
      o[dd].y += __shfl_xor(o[dd].y, off);
      o[dd].z += __shfl_xor(o[dd].z, off);
      o[dd].w += __shfl_xor(o[dd].w, off);
    }
  }
  if (kc == 0) {
    const float inv = 1.f / l_run;
#pragma unroll
    for (int dd = 0; dd < 8; ++dd) {
      float4 w = o[dd];
      w.x *= inv; w.y *= inv; w.z *= inv; w.w *= inv;
      ((float4*)O)[(size_t)(b * NQn + q0 + r) * 64 + h * 8 + dd] = w;
    }
  }
}

// ---------------------------------------------------------------------------
// gemm64 standalone (FFN1): grid (N/64, M/64), 512 threads.
// ---------------------------------------------------------------------------
__global__ __launch_bounds__(512) void gemm64_kernel(
    float* __restrict__ C, const float* __restrict__ A,
    const float* __restrict__ W, const float* __restrict__ bias,
    int ld, int ldc, int do_relu)
{
  __shared__ float smem[4288];
  float (*As)[33] = (float(*)[33])smem;
  float (*WsT)[68] = (float(*)[68])(smem + 2112);
  gemm64_body(C, ldc, A, nullptr, ld, W, bias, ld,
              blockIdx.y * 64, blockIdx.x * 64, blockIdx.x * 64, 1.f, do_relu,
              As, WsT);
}

// ---------------------------------------------------------------------------
// gemm32: 32x32 tile, 256 threads, 2x2/thread, K-step 32, float4 staging with
// register prefetch. Split-K via blockIdx.z (partials at kz*M*N).
// ---------------------------------------------------------------------------
__global__ __launch_bounds__(256) void gemm32_kernel(
    float* __restrict__ C, const float* __restrict__ A, const float* __restrict__ A2,
    const float* __restrict__ W, const float* __restrict__ bias,
    int N, int Kchunk, int Ktot, float scale)
{
  __shared__ float As[32][33];
  __shared__ float Ws[32][33];
  const int bm = blockIdx.y * 32, bn = blockIdx.x * 32;
  const int kz = blockIdx.z;
  const int M = gridDim.y * 32;
  float* Cp = C + (size_t)kz * M * N;
  const int tid = threadIdx.x;
  const int tx = tid & 15, ty = tid >> 4;
  const int lr = tid >> 3, lc = (tid & 7) * 4;
  float acc[2][2] = {};
  const int k00 = kz * Kchunk;
  float4 av, wv;
  {
    av = *(const float4*)(A + (size_t)(bm + lr) * Ktot + k00 + lc);
    if (A2) {
      float4 bv = *(const float4*)(A2 + (size_t)(bm + lr) * Ktot + k00 + lc);
      av.x += bv.x; av.y += bv.y; av.z += bv.z; av.w += bv.w;
    }
    wv = *(const float4*)(W + (size_t)(bn + lr) * Ktot + k00 + lc);
  }
  for (int k0 = k00; k0 < k00 + Kchunk; k0 += 32) {
    As[lr][lc] = av.x; As[lr][lc + 1] = av.y; As[lr][lc + 2] = av.z; As[lr][lc + 3] = av.w;
    Ws[lr][lc] = wv.x; Ws[lr][lc + 1] = wv.y; Ws[lr][lc + 2] = wv.z; Ws[lr][lc + 3] = wv.w;
    __syncthreads();
    if (k0 + 32 < k00 + Kchunk) {
      av = *(const float4*)(A + (size_t)(bm + lr) * Ktot + k0 + 32 + lc);
      if (A2) {
        float4 bv = *(const float4*)(A2 + (size_t)(bm + lr) * Ktot + k0 + 32 + lc);
        av.x += bv.x; av.y += bv.y; av.z += bv.z; av.w += bv.w;
      }
      wv = *(const float4*)(W + (size_t)(bn + lr) * Ktot + k0 + 32 + lc);
    }
#pragma unroll
    for (int k = 0; k < 32; ++k) {
      float a0 = As[ty * 2][k], a1 = As[ty * 2 + 1][k];
      float w0 = Ws[tx * 2][k], w1 = Ws[tx * 2 + 1][k];
      acc[0][0] += a0 * w0; acc[0][1] += a0 * w1;
      acc[1][0] += a1 * w0; acc[1][1] += a1 * w1;
    }
    __syncthreads();
  }
#pragma unroll
  for (int i = 0; i < 2; ++i) {
    int m = bm + ty * 2 + i;
#pragma unroll
    for (int j = 0; j < 2; ++j) {
      int n = bn + tx * 2 + j;
      float v = acc[i][j];
      if (bias) v += bias[n];
      Cp[(size_t)m * N + n] = v * scale;
    }
  }
}

// ---------------------------------------------------------------------------
// out = LayerNorm(x1 + x2) * g + b.  grid: rows, block = 256 = D.
// ---------------------------------------------------------------------------
__global__ __launch_bounds__(256) void add_ln_kernel(
    float* __restrict__ out, const float* __restrict__ x1, const float* __restrict__ x2,
    const float* __restrict__ g, const float* __restrict__ bt)
{
  const int row = blockIdx.x;
  const int t = threadIdx.x;
  const float v = x1[(size_t)row * Dn + t] + x2[(size_t)row * Dn + t];
  float s = v, s2 = v * v;
#pragma unroll
  for (int off = 32; off > 0; off >>= 1) {
    s += __shfl_down(s, off);
    s2 += __shfl_down(s2, off);
  }
  __shared__ float rs[4], rs2[4], fin[2];
  const int lane = t & 63, wid = t >> 6;
  if (lane == 0) { rs[wid] = s; rs2[wid] = s2; }
  __syncthreads();
  if (t == 0) {
    float a = rs[0] + rs[1] + rs[2] + rs[3];
    float a2 = rs2[0] + rs2[1] + rs2[2] + rs2[3];
    float mean = a * (1.f / Dn);
    float var = a2 * (1.f / Dn) - mean * mean;
    fin[0] = mean;
    fin[1] = rsqrtf(var + EPSf);
  }
  __syncthreads();
  out[(size_t)row * Dn + t] = (v - fin[0]) * fin[1] * g[t] + bt[t];
}

// ---------------------------------------------------------------------------
// out = LayerNorm(resid + sum_{kz<4} part[kz] + bias) * g + b (split-K reduce)
// ---------------------------------------------------------------------------
__global__ __launch_bounds__(256) void reduce_ln_kernel(
    float* __restrict__ out, const float* __restrict__ part,
    const float* __restrict__ bias, const float* __restrict__ resid,
    const float* __restrict__ g, const float* __restrict__ bt)
{
  const int row = blockIdx.x;
  const int t = threadIdx.x;
  const size_t idx = (size_t)row * Dn + t;
  const size_t STR = (size_t)Bb * NQn * Dn;
  float v = part[idx] + part[idx + STR] + part[idx + 2 * STR] + part[idx + 3 * STR]
          + bias[t] + resid[idx];
  float s = v, s2 = v * v;
#pragma unroll
  for (int off = 32; off > 0; off >>= 1) {
    s += __shfl_down(s, off);
    s2 += __shfl_down(s2, off);
  }
  __shared__ float rs[4], rs2[4], fin[2];
  const int lane = t & 63, wid = t >> 6;
  if (lane == 0) { rs[wid] = s; rs2[wid] = s2; }
  __syncthreads();
  if (t == 0) {
    float a = rs[0] + rs[1] + rs[2] + rs[3];
    float a2 = rs2[0] + rs2[1] + rs2[2] + rs2[3];
    float mean = a * (1.f / Dn);
    float var = a2 * (1.f / Dn) - mean * mean;
    fin[0] = mean;
    fin[1] = rsqrtf(var + EPSf);
  }
  __syncthreads();
  out[idx] = (v - fin[0]) * fin[1] * g[t] + bt[t];
}

extern "C" void kernel_launch(void* const* d_in, const int* in_sizes, int n_in,
                              void* d_out, int out_size, void* d_ws, size_t ws_size,
                              hipStream_t stream)
{
  const float* tgt   = (const float*)d_in[0];
  const float* qpos  = (const float*)d_in[1];
  const float* src   = (const float*)d_in[2];
  const float* spe   = (const float*)d_in[3];
  const float* pad   = (const float*)d_in[4];
  const float* rel   = (const float*)d_in[5];
  const float* qw    = (const float*)d_in[6];
  const float* qb    = (const float*)d_in[7];
  const float* kw    = (const float*)d_in[8];
  const float* kb    = (const float*)d_in[9];
  const float* vw    = (const float*)d_in[10];
  const float* vb    = (const float*)d_in[11];
  const float* projw = (const float*)d_in[12];
  const float* projb = (const float*)d_in[13];
  const float* cpbw1 = (const float*)d_in[14];
  const float* cpbb1 = (const float*)d_in[15];
  const float* cpbw2 = (const float*)d_in[16];
  const float* ipw   = (const float*)d_in[17];
  const float* ipb   = (const float*)d_in[18];
  const float* outw  = (const float*)d_in[19];
  const float* outb  = (const float*)d_in[20];
  const float* ln1g  = (const float*)d_in[21];
  const float* ln1b  = (const float*)d_in[22];
  const float* ln2g  = (const float*)d_in[23];
  const float* ln2b  = (const float*)d_in[24];
  const float* ln3g  = (const float*)d_in[25];
  const float* ln3b  = (const float*)d_in[26];
  const float* ff1w  = (const float*)d_in[27];
  const float* ff1b  = (const float*)d_in[28];
  const float* ff2w  = (const float*)d_in[29];
  const float* ff2b  = (const float*)d_in[30];
  float* out = (float*)d_out;
  float* ws = (float*)d_ws;

  constexpr size_t SZ_Q   = (size_t)Bb * NQn * Dn;   // 131072
  constexpr size_t SZ_S   = (size_t)Bb * NSn * Dn;   // 524288
  constexpr size_t SZ_FFH = (size_t)Bb * NQn * FFNn; // 524288

  float* qSb  = ws;
  float* kSb  = qSb + SZ_Q;
  float* vSb  = kSb + SZ_Q;
  float* oSb  = vSb + SZ_Q;
  float* soP  = oSb + SZ_Q;
  float* tgt2 = soP + SZ_Q;
  float* qCb  = tgt2 + SZ_Q;
  float* kCb  = qCb + SZ_Q;
  float* vCb  = kCb + SZ_S;
  float* oCb  = vCb + SZ_S;
  float* coP  = oCb + SZ_Q;
  float* tgt3 = coP + SZ_Q;
  float* ffh  = tgt3 + SZ_Q;
  float* part = ffh + SZ_FFH;           // 4 * SZ_Q
  float* tsb  = part + 4 * SZ_Q;
  float* Stab = tsb + RPEn;
  float* Btab = Stab + (RPEn + 1) * Hn;
  float* biasb = Btab + (RPEn + 1) * Hn;

  const int MQ = Bb * NQn;  // 512

  // 1. prep: cpb tables + self QKV + cross KV (all independent)
  prep_kernel<<<dim3(96 + 256 + 1), dim3(512), 0, stream>>>(
      qSb, kSb, vSb, kCb, vCb, tgt, qpos, src, spe, ipw, ipb,
      kw, kb, vw, vb, cpbw1, cpbb1, cpbw2, tsb, Stab, Btab);

  // 2. materialize cross-attn bias (search once per (b,q,k), 8 heads)
  bias_kernel<<<dim3(Bb * NQn), dim3(256), 0, stream>>>(
      biasb, rel, pad, tsb, Stab, Btab);

  // 3. self attention (gload_lds double-buffered flash)
  flash_kernel<<<dim3(NQn / 8, Bb * Hn), dim3(256), 0, stream>>>(
      oSb, qSb, kSb, vSb, nullptr, NQn);

  // 4. self out-proj
  gemm32_kernel<<<dim3(Dn / 32, MQ / 32, 1), dim3(256), 0, stream>>>(
      soP, oSb, nullptr, outw, outb, Dn, Dn, Dn, 1.f);

  // 5. tgt2 = LN2(tgt + soP)
  add_ln_kernel<<<dim3(MQ), dim3(256), 0, stream>>>(tgt2, tgt, soP, ln2g, ln2b);

  // 6. cross q
  gemm32_kernel<<<dim3(Dn / 32, MQ / 32, 1), dim3(256), 0, stream>>>(
      qCb, tgt2, qpos, qw, qb, Dn, Dn, Dn, SCALEf);

  // 7. cross attention (gload_lds double-buffered flash + staged bias)
  flash_kernel<<<dim3(NQn / 8, Bb * Hn), dim3(256), 0, stream>>>(
      oCb, qCb, kCb, vCb, biasb, NSn);

  // 8. cross out-proj
  gemm32_kernel<<<dim3(Dn / 32, MQ / 32, 1), dim3(256), 0, stream>>>(
      coP, oCb, nullptr, projw, projb, Dn, Dn, Dn, 1.f);

  // 9. tgt3 = LN1(tgt2 + coP)
  add_ln_kernel<<<dim3(MQ), dim3(256), 0, stream>>>(tgt3, tgt2, coP, ln1g, ln1b);

  // 10. FFN1 (relu)
  gemm64_kernel<<<dim3(FFNn / 64, MQ / 64), dim3(512), 0, stream>>>(
      ffh, tgt3, ff1w, ff1b, Dn, FFNn, 1);

  // 11. FFN2 split-K x4 -> partials
  gemm32_kernel<<<dim3(Dn / 32, MQ / 32, 4), dim3(256), 0, stream>>>(
      part, ffh, nullptr, ff2w, nullptr, Dn, 256, FFNn, 1.f);

  // 12. out = LN3(tgt3 + sum(part) + ff2b)
  reduce_ln_kernel<<<dim3(MQ), dim3(256), 0, stream>>>(
      out, part, ff2b, tgt3, ln3g, ln3b);
}